// Round 3
// baseline (17744.014 us; speedup 1.0000x reference)
//
#include <hip/hip_runtime.h>
#include <hip/hip_bf16.h>

// LSTM (B=256, T=512, I=64, H=512, O=64) on MI355X — round 3.
// Diagnosis from round-2 counters: per-CU L2->L1 weight streaming bound
// (each of 16 CUs re-read 2.25MB/step; MfmaUtil/VALUBusy ~12% per active CU).
// Fix: REGISTER-RESIDENT weights. 128 blocks = 16 batch-slices x 8 hid-slices;
// each block owns 16 batch rows x 64 hids (all 4 gates), weights live in
// 144 VGPR/lane, loaded once. h exchanged via global + per-group (8 block)
// device-scope counter barrier each step. K split across wave pairs
// (waves 0-3: hh ks0-8; waves 4-7: hh ks9-15 + x-part), partials via LDS.

#define T_STEPS 512
#define ISZ 64
#define HSZ 512
#define BATCH 256
#define OSZ 64
#define XPITCH 72
#define PLPITCH 20   // dword pitch for partial-sum LDS (16B aligned, ~2-way banks)

typedef _Float16 f16x8 __attribute__((ext_vector_type(8)));
typedef float f32x4 __attribute__((ext_vector_type(4)));

// ---------------- workspace layout ----------------
#define OFF_WHH  0u          // 2 MB   fp16 packed W_hh fragments
#define OFF_WIH  2097152u    // 256 KB fp16 packed W_ih fragments
#define OFF_BIAS 2359296u    // 8 KB   f32 b_ih+b_hh
#define OFF_WFCT 2367488u    // 128 KB f32 W_fc transposed
#define OFF_H    2498560u    // 512 KB f16 h_glob[2][256][512]
#define OFF_CNT  3022848u    // 1 KB   u32 cnt[16] (64B stride)

// ---------------- pack kernel (unchanged layout) ----------------
// whh_pk[tile][ks][lane][j] = W_hh[tile*16 + (lane&15)][ks*32 + (lane>>4)*8 + j]
// wih_pk[tile][ks][lane][j] = W_ih[...same...]
#define N_WHH (128*16*64)
#define N_WIH (128*2*64)
#define N_BIAS 2048
#define N_WFC (512*64)
#define N_PACK (N_WHH + N_WIH + N_BIAS + N_WFC)

__global__ void pack_kernel(const float* __restrict__ W_ih, const float* __restrict__ W_hh,
                            const float* __restrict__ b_ih, const float* __restrict__ b_hh,
                            const float* __restrict__ W_fc,
                            _Float16* __restrict__ whh_pk, _Float16* __restrict__ wih_pk,
                            float* __restrict__ bias, float* __restrict__ wfcT) {
    int tid = blockIdx.x * 256 + threadIdx.x;
    if (tid < N_WHH) {
        int lane = tid & 63, ks = (tid >> 6) & 15, tile = tid >> 10;
        int g = tile * 16 + (lane & 15);
        int k = ks * 32 + (lane >> 4) * 8;
        const float4* src = (const float4*)(W_hh + (size_t)g * HSZ + k);
        float4 v0 = src[0], v1 = src[1];
        f16x8 o;
        o[0] = (_Float16)v0.x; o[1] = (_Float16)v0.y; o[2] = (_Float16)v0.z; o[3] = (_Float16)v0.w;
        o[4] = (_Float16)v1.x; o[5] = (_Float16)v1.y; o[6] = (_Float16)v1.z; o[7] = (_Float16)v1.w;
        *(f16x8*)(whh_pk + (size_t)tid * 8) = o;
        return;
    }
    tid -= N_WHH;
    if (tid < N_WIH) {
        int lane = tid & 63, ks = (tid >> 6) & 1, tile = tid >> 7;
        int g = tile * 16 + (lane & 15);
        int k = ks * 32 + (lane >> 4) * 8;
        const float4* src = (const float4*)(W_ih + (size_t)g * ISZ + k);
        float4 v0 = src[0], v1 = src[1];
        f16x8 o;
        o[0] = (_Float16)v0.x; o[1] = (_Float16)v0.y; o[2] = (_Float16)v0.z; o[3] = (_Float16)v0.w;
        o[4] = (_Float16)v1.x; o[5] = (_Float16)v1.y; o[6] = (_Float16)v1.z; o[7] = (_Float16)v1.w;
        *(f16x8*)(wih_pk + (size_t)tid * 8) = o;
        return;
    }
    tid -= N_WIH;
    if (tid < N_BIAS) { bias[tid] = b_ih[tid] + b_hh[tid]; return; }
    tid -= N_BIAS;
    if (tid < N_WFC) {
        int j = tid >> 6, o = tid & 63;
        wfcT[j * 64 + o] = W_fc[o * HSZ + j];
    }
}

// ---------------- init: zero h(0) buffer + barrier counters (every call!) ----------------
__global__ void init_kernel(float* __restrict__ hg0, unsigned* __restrict__ cnt) {
    int tid = blockIdx.x * 256 + threadIdx.x;
    if (tid < 65536) hg0[tid] = 0.f;                      // h_glob[0]: 256 KB
    if (blockIdx.x == 0 && threadIdx.x < 16) cnt[threadIdx.x * 16] = 0u;
}

// ---------------- math ----------------
__device__ __forceinline__ float sigmoid_f(float x) {
    return __builtin_amdgcn_rcpf(1.f + __expf(-x));
}
__device__ __forceinline__ float tanh_f(float x) {
    return 1.f - 2.f * __builtin_amdgcn_rcpf(1.f + __expf(2.f * x));
}

// ---------------- main kernel: 128 blocks x 512 threads ----------------
// block = hs*16 + bs  (group members share bs -> same bid%8 -> same XCD under
// round-robin; perf heuristic only, correctness is device-scope).
__global__ __launch_bounds__(512, 2)
void lstm_kernel(const float* __restrict__ x,
                 const _Float16* __restrict__ whh_pk, const _Float16* __restrict__ wih_pk,
                 const float* __restrict__ bias, const float* __restrict__ wfcT,
                 const float* __restrict__ b_fc,
                 _Float16* __restrict__ h_glob,          // [2][256][512] f16
                 unsigned* __restrict__ cnt,             // [16] stride-16 u32
                 float* __restrict__ out) {
    __shared__ _Float16 xb[2][16 * XPITCH];              // 4.6 KB
    __shared__ float pl[16 * 16 * PLPITCH + 4];          // 20.5 KB partial sums

    const int tid  = threadIdx.x;
    const int lane = tid & 63;
    const int w    = tid >> 6;        // wave 0..7
    const int w16  = w & 3;           // hid16 index within block
    const int half = w >> 2;          // K-half: 0 -> hh ks0-8, 1 -> hh ks9-15 + ih
    const int col  = lane & 15;       // B col (gate row in tile) == A row (batch)
    const int kg   = lane >> 4;       // k-group / C row-group
    const int bid  = blockIdx.x;
    const int hs   = bid >> 4;        // hid slice 0..7 (64 hids)
    const int bs   = bid & 15;        // batch slice 0..15 (16 rows)
    const int brow0 = bs * 16;

    // ---- weights -> registers (once; 144 VGPR/lane) ----
    f16x8 wv[9][4];
    #pragma unroll
    for (int i = 0; i < 9; ++i) {
        #pragma unroll
        for (int gb = 0; gb < 4; ++gb) {
            const int tile = gb * 32 + hs * 4 + w16;
            const _Float16* p;
            if (half == 0)      p = whh_pk + ((size_t)(tile * 16 + i) * 64 + lane) * 8;
            else if (i < 7)     p = whh_pk + ((size_t)(tile * 16 + 9 + i) * 64 + lane) * 8;
            else                p = wih_pk + ((size_t)(tile * 2 + (i - 7)) * 64 + lane) * 8;
            wv[i][gb] = *(const f16x8*)p;
        }
    }

    // bias (used by half0 only)
    float bia[4];
    #pragma unroll
    for (int gb = 0; gb < 4; ++gb)
        bia[gb] = bias[gb * 512 + hs * 64 + w16 * 16 + col];

    // x staging: 16 rows x 64 f32 -> f16 LDS, one float2/thread
    const int xs_row = tid >> 5;
    const int xs_col = (tid & 31) * 2;
    const float* xs_base = x + ((size_t)(brow0 + xs_row) * T_STEPS) * ISZ + xs_col;
    {
        float2 v = *(const float2*)xs_base;
        xb[0][xs_row * XPITCH + xs_col]     = (_Float16)v.x;
        xb[0][xs_row * XPITCH + xs_col + 1] = (_Float16)v.y;
    }

    // c state (half0): (batch 4*kg+r, hid hs*64 + w16*16 + col)
    f32x4 cst = (f32x4){0.f, 0.f, 0.f, 0.f};

    unsigned* mycnt = cnt + bs * 16;

    __syncthreads();   // xb[0] visible

    for (int t = 0; t < T_STEPS; ++t) {
        const int cur = t & 1, nxt = cur ^ 1;

        // ---- A-fragments: h(t) from global (t=0 reads zeroed buf), x from LDS ----
        f16x8 af[9];
        const _Float16* hrow = h_glob + ((size_t)cur * BATCH + brow0 + col) * HSZ;
        #pragma unroll
        for (int i = 0; i < 9; ++i) {
            if (half == 0)      af[i] = *(const f16x8*)(hrow + i * 32 + kg * 8);
            else if (i < 7)     af[i] = *(const f16x8*)(hrow + (9 + i) * 32 + kg * 8);
            else                af[i] = *(const f16x8*)(&xb[cur][col * XPITCH + (i - 7) * 32 + kg * 8]);
        }

        // x(t+1) prefetch (hidden under MFMAs)
        float2 xv;
        const bool havex = (t + 1) < T_STEPS;
        if (havex) xv = *(const float2*)(xs_base + (size_t)(t + 1) * ISZ);

        // ---- MFMA: 36 per wave, bias folded into C-init on half0 ----
        f32x4 acc[4];
        #pragma unroll
        for (int gb = 0; gb < 4; ++gb) {
            const float b0 = (half == 0) ? bia[gb] : 0.f;
            acc[gb] = (f32x4){b0, b0, b0, b0};
        }
        #pragma unroll
        for (int i = 0; i < 9; ++i)
            #pragma unroll
            for (int gb = 0; gb < 4; ++gb)
                acc[gb] = __builtin_amdgcn_mfma_f32_16x16x32_f16(af[i], wv[i][gb], acc[gb], 0, 0, 0);

        // ---- K-half partials: waves 4-7 -> LDS ----
        if (half == 1) {
            #pragma unroll
            for (int gb = 0; gb < 4; ++gb)
                *(f32x4*)&pl[((w16 * 4 + gb) * 16 + col) * PLPITCH + kg * 4] = acc[gb];
        }
        __syncthreads();   // S1: partials visible; xb[cur] reads done

        if (havex) {
            xb[nxt][xs_row * XPITCH + xs_col]     = (_Float16)xv.x;
            xb[nxt][xs_row * XPITCH + xs_col + 1] = (_Float16)xv.y;
        }

        // ---- waves 0-3: combine, cell update (all 4 gates in-register), h store ----
        if (half == 0) {
            #pragma unroll
            for (int gb = 0; gb < 4; ++gb)
                acc[gb] += *(const f32x4*)&pl[((w16 * 4 + gb) * 16 + col) * PLPITCH + kg * 4];
            _Float16* hw = h_glob + ((size_t)nxt * BATCH + brow0) * HSZ + hs * 64 + w16 * 16 + col;
            #pragma unroll
            for (int r = 0; r < 4; ++r) {
                float iv = sigmoid_f(acc[0][r]);
                float fv = sigmoid_f(acc[1][r]);
                float gv = tanh_f   (acc[2][r]);
                float ov = sigmoid_f(acc[3][r]);
                float c  = fv * cst[r] + iv * gv;
                cst[r] = c;
                float hv = ov * tanh_f(c);
                hw[(size_t)(4 * kg + r) * HSZ] = (_Float16)hv;
            }
        }

        // ---- group barrier: release -> arrive -> spin -> acquire ----
        __threadfence();          // flush h stores device-wide (release side)
        __syncthreads();          // S2: all threads' stores fenced
        if (tid == 0) {
            atomicAdd(mycnt, 1u); // device-scope by default (m20)
            const unsigned target = 8u * (unsigned)(t + 1);
            int it = 0;
            while (__hip_atomic_load(mycnt, __ATOMIC_RELAXED, __HIP_MEMORY_SCOPE_AGENT) < target) {
                __builtin_amdgcn_s_sleep(1);
                if (++it > 20000) break;   // safety bail (bug -> wrong, not hung)
            }
        }
        __syncthreads();          // S3: block released
        __threadfence();          // acquire: invalidate caches for fresh h(t)
    }

    // ---- FC epilogue on hs==0 blocks; h_T is h_glob[0] (T even) ----
    if (hs == 0) {
        #pragma unroll
        for (int rr = 0; rr < 2; ++rr) {
            const int m = w * 2 + rr;
            const _Float16* hr = h_glob + (size_t)(brow0 + m) * HSZ;
            float acco = b_fc[lane];
            #pragma unroll 8
            for (int j = 0; j < HSZ; ++j) {
                float hv = (float)hr[j];
                hv = fmaxf(hv, 0.f);
                acco = fmaf(hv, wfcT[j * 64 + lane], acco);
            }
            out[(size_t)(brow0 + m) * OSZ + lane] = acco;
        }
    }
}

// ---------------- launch ----------------
extern "C" void kernel_launch(void* const* d_in, const int* in_sizes, int n_in,
                              void* d_out, int out_size, void* d_ws, size_t ws_size,
                              hipStream_t stream) {
    (void)in_sizes; (void)n_in; (void)out_size; (void)ws_size;
    const float* x    = (const float*)d_in[0];
    const float* W_ih = (const float*)d_in[1];
    const float* W_hh = (const float*)d_in[2];
    const float* b_ih = (const float*)d_in[3];
    const float* b_hh = (const float*)d_in[4];
    const float* W_fc = (const float*)d_in[5];
    const float* b_fc = (const float*)d_in[6];
    float* out = (float*)d_out;

    char* wsb = (char*)d_ws;
    _Float16* whh_pk = (_Float16*)(wsb + OFF_WHH);
    _Float16* wih_pk = (_Float16*)(wsb + OFF_WIH);
    float*    bias   = (float*)   (wsb + OFF_BIAS);
    float*    wfcT   = (float*)   (wsb + OFF_WFCT);
    _Float16* h_glob = (_Float16*)(wsb + OFF_H);
    unsigned* cnt    = (unsigned*)(wsb + OFF_CNT);

    hipLaunchKernelGGL(pack_kernel, dim3((N_PACK + 255) / 256), dim3(256), 0, stream,
                       W_ih, W_hh, b_ih, b_hh, W_fc, whh_pk, wih_pk, bias, wfcT);
    hipLaunchKernelGGL(init_kernel, dim3(256), dim3(256), 0, stream,
                       (float*)(wsb + OFF_H), cnt);
    hipLaunchKernelGGL(lstm_kernel, dim3(128), dim3(512), 0, stream,
                       x, whh_pk, wih_pk, bias, wfcT, b_fc, h_glob, cnt, out);
}

// Round 6
// 17523.679 us; speedup vs baseline: 1.0126x; 1.0126x over previous
//
#include <hip/hip_runtime.h>
#include <hip/hip_bf16.h>

// LSTM (B=256, T=512, I=64, H=512, O=64) on MI355X — round 6 (= round-4 kernel,
// unbenched twice due to GPU acquisition timeouts; resubmitted unchanged to
// keep the A/B against round 3 clean).
// Round-3 post-mortem: VGPR_Count=128 proved weights were NOT register-resident;
// __restrict__ let the compiler rematerialize weight loads inside the t-loop,
// and the per-step device-fence buffer_inv pushed those reloads to L3/HBM
// (MfmaUtil/VALUBusy ~0.7%, hbm_bytes 31MB->200MB). This round changes ONE
// thing: force weight register residency.
//   - no __restrict__ on whh_pk/wih_pk/h_glob in lstm_kernel (aliasing with
//     h stores forbids rematerialization)
//   - asm "+v" keep-alive pins each weight fragment (read-write constraint
//     also forbids remat)
//   - x(t+1) prefetch issued before h loads
// Sync/barrier structure is byte-identical to round 3 (it passed).

#define T_STEPS 512
#define ISZ 64
#define HSZ 512
#define BATCH 256
#define OSZ 64
#define XPITCH 72
#define PLPITCH 20   // dword pitch for partial-sum LDS

typedef _Float16 f16x8 __attribute__((ext_vector_type(8)));
typedef float f32x4 __attribute__((ext_vector_type(4)));

#define KEEP(v) asm volatile("" : "+v"(v))

// ---------------- workspace layout ----------------
#define OFF_WHH  0u          // 2 MB   fp16 packed W_hh fragments
#define OFF_WIH  2097152u    // 256 KB fp16 packed W_ih fragments
#define OFF_BIAS 2359296u    // 8 KB   f32 b_ih+b_hh
#define OFF_WFCT 2367488u    // 128 KB f32 W_fc transposed
#define OFF_H    2498560u    // 512 KB f16 h_glob[2][256][512]
#define OFF_CNT  3022848u    // 1 KB   u32 cnt[16] (64B stride)

// ---------------- pack kernel ----------------
// whh_pk[tile][ks][lane][j] = W_hh[tile*16 + (lane&15)][ks*32 + (lane>>4)*8 + j]
// wih_pk[tile][ks][lane][j] = W_ih[...same...]
#define N_WHH (128*16*64)
#define N_WIH (128*2*64)
#define N_BIAS 2048
#define N_WFC (512*64)
#define N_PACK (N_WHH + N_WIH + N_BIAS + N_WFC)

__global__ void pack_kernel(const float* __restrict__ W_ih, const float* __restrict__ W_hh,
                            const float* __restrict__ b_ih, const float* __restrict__ b_hh,
                            const float* __restrict__ W_fc,
                            _Float16* __restrict__ whh_pk, _Float16* __restrict__ wih_pk,
                            float* __restrict__ bias, float* __restrict__ wfcT) {
    int tid = blockIdx.x * 256 + threadIdx.x;
    if (tid < N_WHH) {
        int lane = tid & 63, ks = (tid >> 6) & 15, tile = tid >> 10;
        int g = tile * 16 + (lane & 15);
        int k = ks * 32 + (lane >> 4) * 8;
        const float4* src = (const float4*)(W_hh + (size_t)g * HSZ + k);
        float4 v0 = src[0], v1 = src[1];
        f16x8 o;
        o[0] = (_Float16)v0.x; o[1] = (_Float16)v0.y; o[2] = (_Float16)v0.z; o[3] = (_Float16)v0.w;
        o[4] = (_Float16)v1.x; o[5] = (_Float16)v1.y; o[6] = (_Float16)v1.z; o[7] = (_Float16)v1.w;
        *(f16x8*)(whh_pk + (size_t)tid * 8) = o;
        return;
    }
    tid -= N_WHH;
    if (tid < N_WIH) {
        int lane = tid & 63, ks = (tid >> 6) & 1, tile = tid >> 7;
        int g = tile * 16 + (lane & 15);
        int k = ks * 32 + (lane >> 4) * 8;
        const float4* src = (const float4*)(W_ih + (size_t)g * ISZ + k);
        float4 v0 = src[0], v1 = src[1];
        f16x8 o;
        o[0] = (_Float16)v0.x; o[1] = (_Float16)v0.y; o[2] = (_Float16)v0.z; o[3] = (_Float16)v0.w;
        o[4] = (_Float16)v1.x; o[5] = (_Float16)v1.y; o[6] = (_Float16)v1.z; o[7] = (_Float16)v1.w;
        *(f16x8*)(wih_pk + (size_t)tid * 8) = o;
        return;
    }
    tid -= N_WIH;
    if (tid < N_BIAS) { bias[tid] = b_ih[tid] + b_hh[tid]; return; }
    tid -= N_BIAS;
    if (tid < N_WFC) {
        int j = tid >> 6, o = tid & 63;
        wfcT[j * 64 + o] = W_fc[o * HSZ + j];
    }
}

// ---------------- init: zero h(0) + barrier counters (every call) ----------------
__global__ void init_kernel(float* __restrict__ hg0, unsigned* __restrict__ cnt) {
    int tid = blockIdx.x * 256 + threadIdx.x;
    if (tid < 65536) hg0[tid] = 0.f;                      // h_glob buf 0: 256 KB
    if (blockIdx.x == 0 && threadIdx.x < 16) cnt[threadIdx.x * 16] = 0u;
}

// ---------------- math ----------------
__device__ __forceinline__ float sigmoid_f(float x) {
    return __builtin_amdgcn_rcpf(1.f + __expf(-x));
}
__device__ __forceinline__ float tanh_f(float x) {
    return 1.f - 2.f * __builtin_amdgcn_rcpf(1.f + __expf(2.f * x));
}

// ---------------- main kernel: 128 blocks x 512 threads ----------------
// block = hs*16 + bs; group = fixed bs (8 blocks, all hid slices).
// NOTE: weight/h pointers intentionally NOT __restrict__ (see header comment).
__global__ __launch_bounds__(512, 2)
void lstm_kernel(const float* __restrict__ x,
                 const _Float16* whh_pk, const _Float16* wih_pk,
                 const float* __restrict__ bias, const float* __restrict__ wfcT,
                 const float* __restrict__ b_fc,
                 _Float16* h_glob,                       // [2][256][512] f16
                 unsigned* __restrict__ cnt,             // [16] stride-16 u32
                 float* __restrict__ out) {
    __shared__ _Float16 xb[2][16 * XPITCH];              // 4.6 KB
    __shared__ float pl[16 * 16 * PLPITCH + 4];          // 20.5 KB partial sums

    const int tid  = threadIdx.x;
    const int lane = tid & 63;
    const int w    = tid >> 6;        // wave 0..7
    const int w16  = w & 3;           // hid16 index within block
    const int half = w >> 2;          // K-half: 0 -> hh ks0-8, 1 -> hh ks9-15 + ih
    const int col  = lane & 15;
    const int kg   = lane >> 4;
    const int bid  = blockIdx.x;
    const int hs   = bid >> 4;        // hid slice 0..7
    const int bs   = bid & 15;        // batch slice 0..15
    const int brow0 = bs * 16;

    // ---- weights -> registers, ONCE (144 VGPR/lane) ----
    f16x8 wv[9][4];
    #pragma unroll
    for (int i = 0; i < 9; ++i) {
        #pragma unroll
        for (int gb = 0; gb < 4; ++gb) {
            const int tile = gb * 32 + hs * 4 + w16;
            const _Float16* p;
            if (half == 0)      p = whh_pk + ((size_t)(tile * 16 + i) * 64 + lane) * 8;
            else if (i < 7)     p = whh_pk + ((size_t)(tile * 16 + 9 + i) * 64 + lane) * 8;
            else                p = wih_pk + ((size_t)(tile * 2 + (i - 7)) * 64 + lane) * 8;
            wv[i][gb] = *(const f16x8*)p;
        }
    }
    // pin: read-write asm forbids rematerialization of the loads above
    #pragma unroll
    for (int i = 0; i < 9; ++i) {
        KEEP(wv[i][0]); KEEP(wv[i][1]); KEEP(wv[i][2]); KEEP(wv[i][3]);
    }

    float bia[4];
    #pragma unroll
    for (int gb = 0; gb < 4; ++gb)
        bia[gb] = bias[gb * 512 + hs * 64 + w16 * 16 + col];

    // x staging: 16 rows x 64 f32 -> f16 LDS, one float2/thread
    const int xs_row = tid >> 5;
    const int xs_col = (tid & 31) * 2;
    const float* xs_base = x + ((size_t)(brow0 + xs_row) * T_STEPS) * ISZ + xs_col;
    {
        float2 v = *(const float2*)xs_base;
        xb[0][xs_row * XPITCH + xs_col]     = (_Float16)v.x;
        xb[0][xs_row * XPITCH + xs_col + 1] = (_Float16)v.y;
    }

    // c state (half0 waves): (batch 4*kg+r, hid hs*64 + w16*16 + col)
    f32x4 cst = (f32x4){0.f, 0.f, 0.f, 0.f};

    unsigned* mycnt = cnt + bs * 16;

    __syncthreads();   // xb[0] visible

    for (int t = 0; t < T_STEPS; ++t) {
        const int cur = t & 1, nxt = cur ^ 1;

        // x(t+1) prefetch first (independent of h)
        float2 xv;
        const bool havex = (t + 1) < T_STEPS;
        if (havex) xv = *(const float2*)(xs_base + (size_t)(t + 1) * ISZ);

        // ---- A-fragments: h(t) from global, x from LDS ----
        f16x8 af[9];
        const _Float16* hrow = h_glob + ((size_t)cur * BATCH + brow0 + col) * HSZ;
        #pragma unroll
        for (int i = 0; i < 9; ++i) {
            if (half == 0)      af[i] = *(const f16x8*)(hrow + i * 32 + kg * 8);
            else if (i < 7)     af[i] = *(const f16x8*)(hrow + (9 + i) * 32 + kg * 8);
            else                af[i] = *(const f16x8*)(&xb[cur][col * XPITCH + (i - 7) * 32 + kg * 8]);
        }

        // ---- 36 MFMA / wave; bias folded into C-init on half0 ----
        f32x4 acc[4];
        #pragma unroll
        for (int gb = 0; gb < 4; ++gb) {
            const float b0 = (half == 0) ? bia[gb] : 0.f;
            acc[gb] = (f32x4){b0, b0, b0, b0};
        }
        #pragma unroll
        for (int i = 0; i < 9; ++i)
            #pragma unroll
            for (int gb = 0; gb < 4; ++gb)
                acc[gb] = __builtin_amdgcn_mfma_f32_16x16x32_f16(af[i], wv[i][gb], acc[gb], 0, 0, 0);

        // ---- K-half partials: waves 4-7 -> LDS ----
        if (half == 1) {
            #pragma unroll
            for (int gb = 0; gb < 4; ++gb)
                *(f32x4*)&pl[((w16 * 4 + gb) * 16 + col) * PLPITCH + kg * 4] = acc[gb];
        }
        __syncthreads();   // S1: partials visible; xb[cur] reads done

        if (havex) {
            xb[nxt][xs_row * XPITCH + xs_col]     = (_Float16)xv.x;
            xb[nxt][xs_row * XPITCH + xs_col + 1] = (_Float16)xv.y;
        }

        // ---- waves 0-3: combine halves, cell update, h store ----
        if (half == 0) {
            #pragma unroll
            for (int gb = 0; gb < 4; ++gb)
                acc[gb] += *(const f32x4*)&pl[((w16 * 4 + gb) * 16 + col) * PLPITCH + kg * 4];
            _Float16* hw = h_glob + ((size_t)nxt * BATCH + brow0) * HSZ + hs * 64 + w16 * 16 + col;
            #pragma unroll
            for (int r = 0; r < 4; ++r) {
                float iv = sigmoid_f(acc[0][r]);
                float fv = sigmoid_f(acc[1][r]);
                float gv = tanh_f   (acc[2][r]);
                float ov = sigmoid_f(acc[3][r]);
                float c  = fv * cst[r] + iv * gv;
                cst[r] = c;
                float hv = ov * tanh_f(c);
                hw[(size_t)(4 * kg + r) * HSZ] = (_Float16)hv;
            }
        }

        // ---- group barrier: release -> arrive -> spin -> acquire ----
        __threadfence();          // flush h stores (release)
        __syncthreads();          // S2
        if (tid == 0) {
            atomicAdd(mycnt, 1u); // device-scope
            const unsigned target = 8u * (unsigned)(t + 1);
            int it = 0;
            while (__hip_atomic_load(mycnt, __ATOMIC_RELAXED, __HIP_MEMORY_SCOPE_AGENT) < target) {
                __builtin_amdgcn_s_sleep(1);
                if (++it > 20000) break;   // safety bail
            }
        }
        __syncthreads();          // S3
        __threadfence();          // acquire: invalidate for fresh h(t+1)
    }

    // ---- FC epilogue on hs==0 blocks; final h is in buffer 0 (T even) ----
    if (hs == 0) {
        #pragma unroll
        for (int rr = 0; rr < 2; ++rr) {
            const int m = w * 2 + rr;
            const _Float16* hr = h_glob + (size_t)(brow0 + m) * HSZ;
            float acco = b_fc[lane];
            #pragma unroll 8
            for (int j = 0; j < HSZ; ++j) {
                float hv = (float)hr[j];
                hv = fmaxf(hv, 0.f);
                acco = fmaf(hv, wfcT[j * 64 + lane], acco);
            }
            out[(size_t)(brow0 + m) * OSZ + lane] = acco;
        }
    }
}

// ---------------- launch ----------------
extern "C" void kernel_launch(void* const* d_in, const int* in_sizes, int n_in,
                              void* d_out, int out_size, void* d_ws, size_t ws_size,
                              hipStream_t stream) {
    (void)in_sizes; (void)n_in; (void)out_size; (void)ws_size;
    const float* x    = (const float*)d_in[0];
    const float* W_ih = (const float*)d_in[1];
    const float* W_hh = (const float*)d_in[2];
    const float* b_ih = (const float*)d_in[3];
    const float* b_hh = (const float*)d_in[4];
    const float* W_fc = (const float*)d_in[5];
    const float* b_fc = (const float*)d_in[6];
    float* out = (float*)d_out;

    char* wsb = (char*)d_ws;
    _Float16* whh_pk = (_Float16*)(wsb + OFF_WHH);
    _Float16* wih_pk = (_Float16*)(wsb + OFF_WIH);
    float*    bias   = (float*)   (wsb + OFF_BIAS);
    float*    wfcT   = (float*)   (wsb + OFF_WFCT);
    _Float16* h_glob = (_Float16*)(wsb + OFF_H);
    unsigned* cnt    = (unsigned*)(wsb + OFF_CNT);

    hipLaunchKernelGGL(pack_kernel, dim3((N_PACK + 255) / 256), dim3(256), 0, stream,
                       W_ih, W_hh, b_ih, b_hh, W_fc, whh_pk, wih_pk, bias, wfcT);
    hipLaunchKernelGGL(init_kernel, dim3(256), dim3(256), 0, stream,
                       (float*)(wsb + OFF_H), cnt);
    hipLaunchKernelGGL(lstm_kernel, dim3(128), dim3(512), 0, stream,
                       x, whh_pk, wih_pk, bias, wfcT, b_fc, h_glob, cnt, out);
}

// Round 8
// 17504.216 us; speedup vs baseline: 1.0137x; 1.0011x over previous
//
#include <hip/hip_runtime.h>
#include <hip/hip_bf16.h>

// LSTM (B=256, T=512, I=64, H=512, O=64) on MI355X — round 8 (= round-7 kernel,
// unbenched due to GPU acquisition timeout; resubmitted unchanged to keep the
// A/B against round 6 clean).
// Round-6 post-mortem: KEEP + no-restrict did NOT give residency
// (VGPR_Count=124, dur unchanged 17.5ms). Weights spilled to scratch: the
// backend's occupancy heuristic targeted 4 waves/SIMD (~128-VGPR budget)
// because __launch_bounds__(512,2) only sets the MINIMUM waves/EU.
// This round changes ONE thing: __attribute__((amdgpu_waves_per_eu(2,2)))
// pins the occupancy target to exactly 2 waves/EU -> 256-VGPR regalloc
// budget -> the 144-VGPR weight array (+~80 working set) fits without spill.
// Everything else is byte-identical to round 6.

#define T_STEPS 512
#define ISZ 64
#define HSZ 512
#define BATCH 256
#define OSZ 64
#define XPITCH 72
#define PLPITCH 20   // dword pitch for partial-sum LDS

typedef _Float16 f16x8 __attribute__((ext_vector_type(8)));
typedef float f32x4 __attribute__((ext_vector_type(4)));

#define KEEP(v) asm volatile("" : "+v"(v))

// ---------------- workspace layout ----------------
#define OFF_WHH  0u          // 2 MB   fp16 packed W_hh fragments
#define OFF_WIH  2097152u    // 256 KB fp16 packed W_ih fragments
#define OFF_BIAS 2359296u    // 8 KB   f32 b_ih+b_hh
#define OFF_WFCT 2367488u    // 128 KB f32 W_fc transposed
#define OFF_H    2498560u    // 512 KB f16 h_glob[2][256][512]
#define OFF_CNT  3022848u    // 1 KB   u32 cnt[16] (64B stride)

// ---------------- pack kernel ----------------
// whh_pk[tile][ks][lane][j] = W_hh[tile*16 + (lane&15)][ks*32 + (lane>>4)*8 + j]
// wih_pk[tile][ks][lane][j] = W_ih[...same...]
#define N_WHH (128*16*64)
#define N_WIH (128*2*64)
#define N_BIAS 2048
#define N_WFC (512*64)
#define N_PACK (N_WHH + N_WIH + N_BIAS + N_WFC)

__global__ void pack_kernel(const float* __restrict__ W_ih, const float* __restrict__ W_hh,
                            const float* __restrict__ b_ih, const float* __restrict__ b_hh,
                            const float* __restrict__ W_fc,
                            _Float16* __restrict__ whh_pk, _Float16* __restrict__ wih_pk,
                            float* __restrict__ bias, float* __restrict__ wfcT) {
    int tid = blockIdx.x * 256 + threadIdx.x;
    if (tid < N_WHH) {
        int lane = tid & 63, ks = (tid >> 6) & 15, tile = tid >> 10;
        int g = tile * 16 + (lane & 15);
        int k = ks * 32 + (lane >> 4) * 8;
        const float4* src = (const float4*)(W_hh + (size_t)g * HSZ + k);
        float4 v0 = src[0], v1 = src[1];
        f16x8 o;
        o[0] = (_Float16)v0.x; o[1] = (_Float16)v0.y; o[2] = (_Float16)v0.z; o[3] = (_Float16)v0.w;
        o[4] = (_Float16)v1.x; o[5] = (_Float16)v1.y; o[6] = (_Float16)v1.z; o[7] = (_Float16)v1.w;
        *(f16x8*)(whh_pk + (size_t)tid * 8) = o;
        return;
    }
    tid -= N_WHH;
    if (tid < N_WIH) {
        int lane = tid & 63, ks = (tid >> 6) & 1, tile = tid >> 7;
        int g = tile * 16 + (lane & 15);
        int k = ks * 32 + (lane >> 4) * 8;
        const float4* src = (const float4*)(W_ih + (size_t)g * ISZ + k);
        float4 v0 = src[0], v1 = src[1];
        f16x8 o;
        o[0] = (_Float16)v0.x; o[1] = (_Float16)v0.y; o[2] = (_Float16)v0.z; o[3] = (_Float16)v0.w;
        o[4] = (_Float16)v1.x; o[5] = (_Float16)v1.y; o[6] = (_Float16)v1.z; o[7] = (_Float16)v1.w;
        *(f16x8*)(wih_pk + (size_t)tid * 8) = o;
        return;
    }
    tid -= N_WIH;
    if (tid < N_BIAS) { bias[tid] = b_ih[tid] + b_hh[tid]; return; }
    tid -= N_BIAS;
    if (tid < N_WFC) {
        int j = tid >> 6, o = tid & 63;
        wfcT[j * 64 + o] = W_fc[o * HSZ + j];
    }
}

// ---------------- init: zero h(0) + barrier counters (every call) ----------------
__global__ void init_kernel(float* __restrict__ hg0, unsigned* __restrict__ cnt) {
    int tid = blockIdx.x * 256 + threadIdx.x;
    if (tid < 65536) hg0[tid] = 0.f;                      // h_glob buf 0: 256 KB
    if (blockIdx.x == 0 && threadIdx.x < 16) cnt[threadIdx.x * 16] = 0u;
}

// ---------------- math ----------------
__device__ __forceinline__ float sigmoid_f(float x) {
    return __builtin_amdgcn_rcpf(1.f + __expf(-x));
}
__device__ __forceinline__ float tanh_f(float x) {
    return 1.f - 2.f * __builtin_amdgcn_rcpf(1.f + __expf(2.f * x));
}

// ---------------- main kernel: 128 blocks x 512 threads ----------------
// block = hs*16 + bs; group = fixed bs (8 blocks, all hid slices).
// Weight/h pointers intentionally NOT __restrict__; waves_per_eu(2,2) pins
// the regalloc budget to 256 VGPR/wave so the weight array stays resident.
__global__ void __launch_bounds__(512)
__attribute__((amdgpu_waves_per_eu(2, 2)))
lstm_kernel(const float* __restrict__ x,
            const _Float16* whh_pk, const _Float16* wih_pk,
            const float* __restrict__ bias, const float* __restrict__ wfcT,
            const float* __restrict__ b_fc,
            _Float16* h_glob,                       // [2][256][512] f16
            unsigned* __restrict__ cnt,             // [16] stride-16 u32
            float* __restrict__ out) {
    __shared__ _Float16 xb[2][16 * XPITCH];              // 4.6 KB
    __shared__ float pl[16 * 16 * PLPITCH + 4];          // 20.5 KB partial sums

    const int tid  = threadIdx.x;
    const int lane = tid & 63;
    const int w    = tid >> 6;        // wave 0..7
    const int w16  = w & 3;           // hid16 index within block
    const int half = w >> 2;          // K-half: 0 -> hh ks0-8, 1 -> hh ks9-15 + ih
    const int col  = lane & 15;
    const int kg   = lane >> 4;
    const int bid  = blockIdx.x;
    const int hs   = bid >> 4;        // hid slice 0..7
    const int bs   = bid & 15;        // batch slice 0..15
    const int brow0 = bs * 16;

    // ---- weights -> registers, ONCE (144 VGPR/lane) ----
    f16x8 wv[9][4];
    #pragma unroll
    for (int i = 0; i < 9; ++i) {
        #pragma unroll
        for (int gb = 0; gb < 4; ++gb) {
            const int tile = gb * 32 + hs * 4 + w16;
            const _Float16* p;
            if (half == 0)      p = whh_pk + ((size_t)(tile * 16 + i) * 64 + lane) * 8;
            else if (i < 7)     p = whh_pk + ((size_t)(tile * 16 + 9 + i) * 64 + lane) * 8;
            else                p = wih_pk + ((size_t)(tile * 2 + (i - 7)) * 64 + lane) * 8;
            wv[i][gb] = *(const f16x8*)p;
        }
    }
    // pin: read-write asm forbids rematerialization of the loads above
    #pragma unroll
    for (int i = 0; i < 9; ++i) {
        KEEP(wv[i][0]); KEEP(wv[i][1]); KEEP(wv[i][2]); KEEP(wv[i][3]);
    }

    float bia[4];
    #pragma unroll
    for (int gb = 0; gb < 4; ++gb)
        bia[gb] = bias[gb * 512 + hs * 64 + w16 * 16 + col];

    // x staging: 16 rows x 64 f32 -> f16 LDS, one float2/thread
    const int xs_row = tid >> 5;
    const int xs_col = (tid & 31) * 2;
    const float* xs_base = x + ((size_t)(brow0 + xs_row) * T_STEPS) * ISZ + xs_col;
    {
        float2 v = *(const float2*)xs_base;
        xb[0][xs_row * XPITCH + xs_col]     = (_Float16)v.x;
        xb[0][xs_row * XPITCH + xs_col + 1] = (_Float16)v.y;
    }

    // c state (half0 waves): (batch 4*kg+r, hid hs*64 + w16*16 + col)
    f32x4 cst = (f32x4){0.f, 0.f, 0.f, 0.f};

    unsigned* mycnt = cnt + bs * 16;

    __syncthreads();   // xb[0] visible

    for (int t = 0; t < T_STEPS; ++t) {
        const int cur = t & 1, nxt = cur ^ 1;

        // x(t+1) prefetch first (independent of h)
        float2 xv;
        const bool havex = (t + 1) < T_STEPS;
        if (havex) xv = *(const float2*)(xs_base + (size_t)(t + 1) * ISZ);

        // ---- A-fragments: h(t) from global, x from LDS ----
        f16x8 af[9];
        const _Float16* hrow = h_glob + ((size_t)cur * BATCH + brow0 + col) * HSZ;
        #pragma unroll
        for (int i = 0; i < 9; ++i) {
            if (half == 0)      af[i] = *(const f16x8*)(hrow + i * 32 + kg * 8);
            else if (i < 7)     af[i] = *(const f16x8*)(hrow + (9 + i) * 32 + kg * 8);
            else                af[i] = *(const f16x8*)(&xb[cur][col * XPITCH + (i - 7) * 32 + kg * 8]);
        }

        // ---- 36 MFMA / wave; bias folded into C-init on half0 ----
        f32x4 acc[4];
        #pragma unroll
        for (int gb = 0; gb < 4; ++gb) {
            const float b0 = (half == 0) ? bia[gb] : 0.f;
            acc[gb] = (f32x4){b0, b0, b0, b0};
        }
        #pragma unroll
        for (int i = 0; i < 9; ++i)
            #pragma unroll
            for (int gb = 0; gb < 4; ++gb)
                acc[gb] = __builtin_amdgcn_mfma_f32_16x16x32_f16(af[i], wv[i][gb], acc[gb], 0, 0, 0);

        // ---- K-half partials: waves 4-7 -> LDS ----
        if (half == 1) {
            #pragma unroll
            for (int gb = 0; gb < 4; ++gb)
                *(f32x4*)&pl[((w16 * 4 + gb) * 16 + col) * PLPITCH + kg * 4] = acc[gb];
        }
        __syncthreads();   // S1: partials visible; xb[cur] reads done

        if (havex) {
            xb[nxt][xs_row * XPITCH + xs_col]     = (_Float16)xv.x;
            xb[nxt][xs_row * XPITCH + xs_col + 1] = (_Float16)xv.y;
        }

        // ---- waves 0-3: combine halves, cell update, h store ----
        if (half == 0) {
            #pragma unroll
            for (int gb = 0; gb < 4; ++gb)
                acc[gb] += *(const f32x4*)&pl[((w16 * 4 + gb) * 16 + col) * PLPITCH + kg * 4];
            _Float16* hw = h_glob + ((size_t)nxt * BATCH + brow0) * HSZ + hs * 64 + w16 * 16 + col;
            #pragma unroll
            for (int r = 0; r < 4; ++r) {
                float iv = sigmoid_f(acc[0][r]);
                float fv = sigmoid_f(acc[1][r]);
                float gv = tanh_f   (acc[2][r]);
                float ov = sigmoid_f(acc[3][r]);
                float c  = fv * cst[r] + iv * gv;
                cst[r] = c;
                float hv = ov * tanh_f(c);
                hw[(size_t)(4 * kg + r) * HSZ] = (_Float16)hv;
            }
        }

        // ---- group barrier: release -> arrive -> spin -> acquire ----
        __threadfence();          // flush h stores (release)
        __syncthreads();          // S2
        if (tid == 0) {
            atomicAdd(mycnt, 1u); // device-scope
            const unsigned target = 8u * (unsigned)(t + 1);
            int it = 0;
            while (__hip_atomic_load(mycnt, __ATOMIC_RELAXED, __HIP_MEMORY_SCOPE_AGENT) < target) {
                __builtin_amdgcn_s_sleep(1);
                if (++it > 20000) break;   // safety bail
            }
        }
        __syncthreads();          // S3
        __threadfence();          // acquire: invalidate for fresh h(t+1)
    }

    // ---- FC epilogue on hs==0 blocks; final h is in buffer 0 (T even) ----
    if (hs == 0) {
        #pragma unroll
        for (int rr = 0; rr < 2; ++rr) {
            const int m = w * 2 + rr;
            const _Float16* hr = h_glob + (size_t)(brow0 + m) * HSZ;
            float acco = b_fc[lane];
            #pragma unroll 8
            for (int j = 0; j < HSZ; ++j) {
                float hv = (float)hr[j];
                hv = fmaxf(hv, 0.f);
                acco = fmaf(hv, wfcT[j * 64 + lane], acco);
            }
            out[(size_t)(brow0 + m) * OSZ + lane] = acco;
        }
    }
}

// ---------------- launch ----------------
extern "C" void kernel_launch(void* const* d_in, const int* in_sizes, int n_in,
                              void* d_out, int out_size, void* d_ws, size_t ws_size,
                              hipStream_t stream) {
    (void)in_sizes; (void)n_in; (void)out_size; (void)ws_size;
    const float* x    = (const float*)d_in[0];
    const float* W_ih = (const float*)d_in[1];
    const float* W_hh = (const float*)d_in[2];
    const float* b_ih = (const float*)d_in[3];
    const float* b_hh = (const float*)d_in[4];
    const float* W_fc = (const float*)d_in[5];
    const float* b_fc = (const float*)d_in[6];
    float* out = (float*)d_out;

    char* wsb = (char*)d_ws;
    _Float16* whh_pk = (_Float16*)(wsb + OFF_WHH);
    _Float16* wih_pk = (_Float16*)(wsb + OFF_WIH);
    float*    bias   = (float*)   (wsb + OFF_BIAS);
    float*    wfcT   = (float*)   (wsb + OFF_WFCT);
    _Float16* h_glob = (_Float16*)(wsb + OFF_H);
    unsigned* cnt    = (unsigned*)(wsb + OFF_CNT);

    hipLaunchKernelGGL(pack_kernel, dim3((N_PACK + 255) / 256), dim3(256), 0, stream,
                       W_ih, W_hh, b_ih, b_hh, W_fc, whh_pk, wih_pk, bias, wfcT);
    hipLaunchKernelGGL(init_kernel, dim3(256), dim3(256), 0, stream,
                       (float*)(wsb + OFF_H), cnt);
    hipLaunchKernelGGL(lstm_kernel, dim3(128), dim3(512), 0, stream,
                       x, whh_pk, wih_pk, bias, wfcT, b_fc, h_glob, cnt, out);
}

// Round 9
// 2852.961 us; speedup vs baseline: 6.2195x; 6.1355x over previous
//
#include <hip/hip_runtime.h>
#include <hip/hip_bf16.h>

// LSTM (B=256, T=512, I=64, H=512, O=64) on MI355X — round 9.
// Round-8 post-mortem: residency levers dead (VGPR 124 both rounds, dur
// unchanged). Counter accounting fingered the REAL bottleneck: two
// __threadfence() per block per step -> per-XCD L2 writeback-invalidate storm
// (WRITE_SIZE 133MB @ HBM = the h stores; ~30us/step unaccounted by any
// compute/BW term; 16 blocks/XCD x 2 fences serialized).
// THIS ROUND: fence-free h exchange.
//   - h stores/loads via __hip_atomic_* RELAXED + MEMORY_SCOPE_AGENT
//     (write-through to L3, L2-bypass reads -> no wb/inv instructions at all)
//   - h store coalesced: cell results -> 2KB LDS tile -> one u32 agent store
//     per thread; __syncthreads' implicit vmcnt(0) drain + barrier orders the
//     stores before the group counter atomicAdd (release); spin + barrier = acquire
//   - NO __threadfence anywhere in the loop
//   - weights/scratch/x now stay warm in XCD L2 across all 512 steps
// Everything else (partition, MFMA layout, pack, barrier counters) = round 8.

#define T_STEPS 512
#define ISZ 64
#define HSZ 512
#define BATCH 256
#define OSZ 64
#define XPITCH 72
#define PLPITCH 20   // dword pitch for partial-sum LDS

typedef _Float16 f16x8 __attribute__((ext_vector_type(8)));
typedef float f32x4 __attribute__((ext_vector_type(4)));

#define KEEP(v) asm volatile("" : "+v"(v))

// ---------------- workspace layout ----------------
#define OFF_WHH  0u          // 2 MB   fp16 packed W_hh fragments
#define OFF_WIH  2097152u    // 256 KB fp16 packed W_ih fragments
#define OFF_BIAS 2359296u    // 8 KB   f32 b_ih+b_hh
#define OFF_WFCT 2367488u    // 128 KB f32 W_fc transposed
#define OFF_H    2498560u    // 512 KB f16 h_glob[2][256][512]
#define OFF_CNT  3022848u    // 1 KB   u32 cnt[16] (64B stride)

// ---------------- pack kernel ----------------
// whh_pk[tile][ks][lane][j] = W_hh[tile*16 + (lane&15)][ks*32 + (lane>>4)*8 + j]
// wih_pk[tile][ks][lane][j] = W_ih[...same...]
#define N_WHH (128*16*64)
#define N_WIH (128*2*64)
#define N_BIAS 2048
#define N_WFC (512*64)
#define N_PACK (N_WHH + N_WIH + N_BIAS + N_WFC)

__global__ void pack_kernel(const float* __restrict__ W_ih, const float* __restrict__ W_hh,
                            const float* __restrict__ b_ih, const float* __restrict__ b_hh,
                            const float* __restrict__ W_fc,
                            _Float16* __restrict__ whh_pk, _Float16* __restrict__ wih_pk,
                            float* __restrict__ bias, float* __restrict__ wfcT) {
    int tid = blockIdx.x * 256 + threadIdx.x;
    if (tid < N_WHH) {
        int lane = tid & 63, ks = (tid >> 6) & 15, tile = tid >> 10;
        int g = tile * 16 + (lane & 15);
        int k = ks * 32 + (lane >> 4) * 8;
        const float4* src = (const float4*)(W_hh + (size_t)g * HSZ + k);
        float4 v0 = src[0], v1 = src[1];
        f16x8 o;
        o[0] = (_Float16)v0.x; o[1] = (_Float16)v0.y; o[2] = (_Float16)v0.z; o[3] = (_Float16)v0.w;
        o[4] = (_Float16)v1.x; o[5] = (_Float16)v1.y; o[6] = (_Float16)v1.z; o[7] = (_Float16)v1.w;
        *(f16x8*)(whh_pk + (size_t)tid * 8) = o;
        return;
    }
    tid -= N_WHH;
    if (tid < N_WIH) {
        int lane = tid & 63, ks = (tid >> 6) & 1, tile = tid >> 7;
        int g = tile * 16 + (lane & 15);
        int k = ks * 32 + (lane >> 4) * 8;
        const float4* src = (const float4*)(W_ih + (size_t)g * ISZ + k);
        float4 v0 = src[0], v1 = src[1];
        f16x8 o;
        o[0] = (_Float16)v0.x; o[1] = (_Float16)v0.y; o[2] = (_Float16)v0.z; o[3] = (_Float16)v0.w;
        o[4] = (_Float16)v1.x; o[5] = (_Float16)v1.y; o[6] = (_Float16)v1.z; o[7] = (_Float16)v1.w;
        *(f16x8*)(wih_pk + (size_t)tid * 8) = o;
        return;
    }
    tid -= N_WIH;
    if (tid < N_BIAS) { bias[tid] = b_ih[tid] + b_hh[tid]; return; }
    tid -= N_BIAS;
    if (tid < N_WFC) {
        int j = tid >> 6, o = tid & 63;
        wfcT[j * 64 + o] = W_fc[o * HSZ + j];
    }
}

// ---------------- init: zero h(0) + barrier counters (every call) ----------------
__global__ void init_kernel(float* __restrict__ hg0, unsigned* __restrict__ cnt) {
    int tid = blockIdx.x * 256 + threadIdx.x;
    if (tid < 65536) hg0[tid] = 0.f;                      // h_glob buf 0: 256 KB
    if (blockIdx.x == 0 && threadIdx.x < 16) cnt[threadIdx.x * 16] = 0u;
}

// ---------------- math ----------------
__device__ __forceinline__ float sigmoid_f(float x) {
    return __builtin_amdgcn_rcpf(1.f + __expf(-x));
}
__device__ __forceinline__ float tanh_f(float x) {
    return 1.f - 2.f * __builtin_amdgcn_rcpf(1.f + __expf(2.f * x));
}

// agent-scope (device-visible, L2-bypass) 16B h-fragment load as 2x u64
__device__ __forceinline__ f16x8 ld_h8_agent(const _Float16* p) {
    union { unsigned long long u[2]; f16x8 v; } r;
    r.u[0] = __hip_atomic_load((const unsigned long long*)p,
                               __ATOMIC_RELAXED, __HIP_MEMORY_SCOPE_AGENT);
    r.u[1] = __hip_atomic_load((const unsigned long long*)(p + 4),
                               __ATOMIC_RELAXED, __HIP_MEMORY_SCOPE_AGENT);
    return r.v;
}

// ---------------- main kernel: 128 blocks x 512 threads ----------------
// block = hs*16 + bs; group = fixed bs (8 blocks, all hid slices).
__global__ void __launch_bounds__(512)
__attribute__((amdgpu_waves_per_eu(2, 2)))
lstm_kernel(const float* __restrict__ x,
            const _Float16* whh_pk, const _Float16* wih_pk,
            const float* __restrict__ bias, const float* __restrict__ wfcT,
            const float* __restrict__ b_fc,
            _Float16* h_glob,                       // [2][256][512] f16
            unsigned* __restrict__ cnt,             // [16] stride-16 u32
            float* __restrict__ out) {
    __shared__ _Float16 xb[2][16 * XPITCH];              // 4.6 KB
    __shared__ float pl[16 * 16 * PLPITCH + 4];          // 20.5 KB partial sums
    __shared__ _Float16 hst[16 * 64];                    // 2 KB h-staging tile

    const int tid  = threadIdx.x;
    const int lane = tid & 63;
    const int w    = tid >> 6;        // wave 0..7
    const int w16  = w & 3;           // hid16 index within block
    const int half = w >> 2;          // K-half: 0 -> hh ks0-8, 1 -> hh ks9-15 + ih
    const int col  = lane & 15;
    const int kg   = lane >> 4;
    const int bid  = blockIdx.x;
    const int hs   = bid >> 4;        // hid slice 0..7
    const int bs   = bid & 15;        // batch slice 0..15
    const int brow0 = bs * 16;

    // ---- weights -> registers (or warm-L2 scratch; fences are gone so either is cheap) ----
    f16x8 wv[9][4];
    #pragma unroll
    for (int i = 0; i < 9; ++i) {
        #pragma unroll
        for (int gb = 0; gb < 4; ++gb) {
            const int tile = gb * 32 + hs * 4 + w16;
            const _Float16* p;
            if (half == 0)      p = whh_pk + ((size_t)(tile * 16 + i) * 64 + lane) * 8;
            else if (i < 7)     p = whh_pk + ((size_t)(tile * 16 + 9 + i) * 64 + lane) * 8;
            else                p = wih_pk + ((size_t)(tile * 2 + (i - 7)) * 64 + lane) * 8;
            wv[i][gb] = *(const f16x8*)p;
        }
    }
    #pragma unroll
    for (int i = 0; i < 9; ++i) {
        KEEP(wv[i][0]); KEEP(wv[i][1]); KEEP(wv[i][2]); KEEP(wv[i][3]);
    }

    float bia[4];
    #pragma unroll
    for (int gb = 0; gb < 4; ++gb)
        bia[gb] = bias[gb * 512 + hs * 64 + w16 * 16 + col];

    // x staging: 16 rows x 64 f32 -> f16 LDS, one float2/thread
    const int xs_row = tid >> 5;
    const int xs_col = (tid & 31) * 2;
    const float* xs_base = x + ((size_t)(brow0 + xs_row) * T_STEPS) * ISZ + xs_col;
    {
        float2 v = *(const float2*)xs_base;
        xb[0][xs_row * XPITCH + xs_col]     = (_Float16)v.x;
        xb[0][xs_row * XPITCH + xs_col + 1] = (_Float16)v.y;
    }

    // c state (half0 waves): (batch 4*kg+r, hid hs*64 + w16*16 + col)
    f32x4 cst = (f32x4){0.f, 0.f, 0.f, 0.f};

    unsigned* mycnt = cnt + bs * 16;

    __syncthreads();   // xb[0] visible

    for (int t = 0; t < T_STEPS; ++t) {
        const int cur = t & 1, nxt = cur ^ 1;

        // x(t+1) prefetch (independent of h)
        float2 xv;
        const bool havex = (t + 1) < T_STEPS;
        if (havex) xv = *(const float2*)(xs_base + (size_t)(t + 1) * ISZ);

        // ---- A-fragments: h(t) via agent loads (L3-fresh), x from LDS ----
        f16x8 af[9];
        const _Float16* hrow = h_glob + ((size_t)cur * BATCH + brow0 + col) * HSZ;
        #pragma unroll
        for (int i = 0; i < 9; ++i) {
            if (half == 0)      af[i] = ld_h8_agent(hrow + i * 32 + kg * 8);
            else if (i < 7)     af[i] = ld_h8_agent(hrow + (9 + i) * 32 + kg * 8);
            else                af[i] = *(const f16x8*)(&xb[cur][col * XPITCH + (i - 7) * 32 + kg * 8]);
        }

        // ---- 36 MFMA / wave; bias folded into C-init on half0 ----
        f32x4 acc[4];
        #pragma unroll
        for (int gb = 0; gb < 4; ++gb) {
            const float b0 = (half == 0) ? bia[gb] : 0.f;
            acc[gb] = (f32x4){b0, b0, b0, b0};
        }
        #pragma unroll
        for (int i = 0; i < 9; ++i)
            #pragma unroll
            for (int gb = 0; gb < 4; ++gb)
                acc[gb] = __builtin_amdgcn_mfma_f32_16x16x32_f16(af[i], wv[i][gb], acc[gb], 0, 0, 0);

        // ---- K-half partials: waves 4-7 -> LDS ----
        if (half == 1) {
            #pragma unroll
            for (int gb = 0; gb < 4; ++gb)
                *(f32x4*)&pl[((w16 * 4 + gb) * 16 + col) * PLPITCH + kg * 4] = acc[gb];
        }
        __syncthreads();   // S1: partials visible; xb[cur] reads done

        if (havex) {
            xb[nxt][xs_row * XPITCH + xs_col]     = (_Float16)xv.x;
            xb[nxt][xs_row * XPITCH + xs_col + 1] = (_Float16)xv.y;
        }

        // ---- waves 0-3: combine halves, cell update, h -> LDS staging tile ----
        if (half == 0) {
            #pragma unroll
            for (int gb = 0; gb < 4; ++gb)
                acc[gb] += *(const f32x4*)&pl[((w16 * 4 + gb) * 16 + col) * PLPITCH + kg * 4];
            #pragma unroll
            for (int r = 0; r < 4; ++r) {
                float iv = sigmoid_f(acc[0][r]);
                float fv = sigmoid_f(acc[1][r]);
                float gv = tanh_f   (acc[2][r]);
                float ov = sigmoid_f(acc[3][r]);
                float c  = fv * cst[r] + iv * gv;
                cst[r] = c;
                float hv = ov * tanh_f(c);
                hst[(4 * kg + r) * 64 + w16 * 16 + col] = (_Float16)hv;
            }
        }
        __syncthreads();   // S2: hst complete

        // ---- cooperative coalesced agent store: 512 threads x one u32 ----
        {
            const int b   = tid >> 5;       // batch row 0..15
            const int c32 = tid & 31;       // u32 column 0..31 (64 f16)
            unsigned v = *(const unsigned*)&hst[b * 64 + c32 * 2];
            unsigned* dst = (unsigned*)(h_glob + ((size_t)nxt * BATCH + brow0 + b) * HSZ + hs * 64) + c32;
            __hip_atomic_store(dst, v, __ATOMIC_RELAXED, __HIP_MEMORY_SCOPE_AGENT);
        }
        __syncthreads();   // S3: implicit vmcnt(0) drains the agent stores (release)

        // ---- group barrier: arrive -> spin (no fences) ----
        if (tid == 0) {
            atomicAdd(mycnt, 1u);           // device-scope, relaxed
            const unsigned target = 8u * (unsigned)(t + 1);
            int it = 0;
            while (__hip_atomic_load(mycnt, __ATOMIC_RELAXED, __HIP_MEMORY_SCOPE_AGENT) < target) {
                __builtin_amdgcn_s_sleep(1);
                if (++it > 20000) break;    // safety bail (bug -> wrong, not hung)
            }
        }
        __syncthreads();   // S4: block released; next step's agent loads read L3 fresh
    }

    // ---- FC epilogue on hs==0 blocks; final h is in buffer 0 (T even) ----
    if (hs == 0) {
        #pragma unroll
        for (int rr = 0; rr < 2; ++rr) {
            const int m = w * 2 + rr;
            const _Float16* hr = h_glob + (size_t)(brow0 + m) * HSZ;
            float acco = b_fc[lane];
            for (int j8 = 0; j8 < HSZ / 8; ++j8) {
                f16x8 hv8 = ld_h8_agent(hr + j8 * 8);
                #pragma unroll
                for (int j = 0; j < 8; ++j) {
                    float hv = fmaxf((float)hv8[j], 0.f);
                    acco = fmaf(hv, wfcT[(j8 * 8 + j) * 64 + lane], acco);
                }
            }
            out[(size_t)(brow0 + m) * OSZ + lane] = acco;
        }
    }
}

// ---------------- launch ----------------
extern "C" void kernel_launch(void* const* d_in, const int* in_sizes, int n_in,
                              void* d_out, int out_size, void* d_ws, size_t ws_size,
                              hipStream_t stream) {
    (void)in_sizes; (void)n_in; (void)out_size; (void)ws_size;
    const float* x    = (const float*)d_in[0];
    const float* W_ih = (const float*)d_in[1];
    const float* W_hh = (const float*)d_in[2];
    const float* b_ih = (const float*)d_in[3];
    const float* b_hh = (const float*)d_in[4];
    const float* W_fc = (const float*)d_in[5];
    const float* b_fc = (const float*)d_in[6];
    float* out = (float*)d_out;

    char* wsb = (char*)d_ws;
    _Float16* whh_pk = (_Float16*)(wsb + OFF_WHH);
    _Float16* wih_pk = (_Float16*)(wsb + OFF_WIH);
    float*    bias   = (float*)   (wsb + OFF_BIAS);
    float*    wfcT   = (float*)   (wsb + OFF_WFCT);
    _Float16* h_glob = (_Float16*)(wsb + OFF_H);
    unsigned* cnt    = (unsigned*)(wsb + OFF_CNT);

    hipLaunchKernelGGL(pack_kernel, dim3((N_PACK + 255) / 256), dim3(256), 0, stream,
                       W_ih, W_hh, b_ih, b_hh, W_fc, whh_pk, wih_pk, bias, wfcT);
    hipLaunchKernelGGL(init_kernel, dim3(256), dim3(256), 0, stream,
                       (float*)(wsb + OFF_H), cnt);
    hipLaunchKernelGGL(lstm_kernel, dim3(128), dim3(512), 0, stream,
                       x, whh_pk, wih_pk, bias, wfcT, b_fc, h_glob, cnt, out);
}

// Round 10
// 2832.206 us; speedup vs baseline: 6.2651x; 1.0073x over previous
//
#include <hip/hip_runtime.h>
#include <hip/hip_bf16.h>

// LSTM (B=256, T=512, I=64, H=512, O=64) on MI355X — round 10.
// r9 confirmed the fence theory (17.5 -> 2.85 ms). New budget: weight
// streaming from warm L2 ~2.1us/step is the largest term (VGPR=116: compiler
// refuses residency; two failed rounds). THIS ROUND: weights -> LDS, where
// residency is under source control.
//   - 256 blocks = 16 bs x 16 hs; block = 16 batch x 32 hids, all 4 gates
//   - W_hh slice (128 KB) staged to dynamic LDS once (hipFuncSetAttribute
//     to raise the 64 KB cap); W_ih slice (16 VGPR) in registers
//   - 4 waves, output-split: wave (p,ro) = hid16-half p, gates {i,f}/{g,o};
//     full K per wave -> no K-partials; g,o cross via 5 KB LDS tile
//   - h exchange: agent-scope relaxed atomics, fence-free (r9 protocol);
//     group barrier now 16 arrivals (all hs blocks of one bs)
//   - waves_per_eu(1,1): 1 block/CU, 512-VGPR budget (demand ~150, no spill)

#define T_STEPS 512
#define ISZ 64
#define HSZ 512
#define BATCH 256
#define OSZ 64
#define XPITCH 72    // f16 pitch; 144 B = 16B-aligned rows for b128 reads
#define PLP 20       // dword pitch for g/o partial tile

typedef _Float16 f16x8 __attribute__((ext_vector_type(8)));
typedef _Float16 f16x4 __attribute__((ext_vector_type(4)));
typedef float f32x4 __attribute__((ext_vector_type(4)));

#define KEEP(v) asm volatile("" : "+v"(v))

// ---------------- workspace layout (unchanged from r9) ----------------
#define OFF_WHH  0u          // 2 MB   fp16 packed W_hh fragments
#define OFF_WIH  2097152u    // 256 KB fp16 packed W_ih fragments
#define OFF_BIAS 2359296u    // 8 KB   f32 b_ih+b_hh
#define OFF_WFCT 2367488u    // 128 KB f32 W_fc transposed
#define OFF_H    2498560u    // 512 KB f16 h_glob[2][256][512]
#define OFF_CNT  3022848u    // 1 KB   u32 cnt[16] (64B stride)

// ---------------- dynamic-LDS partition ----------------
#define LDS_WHH   0u         // 131072 B : 8 tiles x 16 ks x 64 lanes x 16 B
#define LDS_XB    131072u    //   4608 B : 2 x 16 x 72 f16
#define LDS_PL    135680u    //   5120 B : g/o partials, 4 tiles x 16 x 20 dw
#define LDS_HST   140800u    //   1024 B : 16 x 32 f16 h staging
#define LDS_TOTAL 141824u

// ---------------- pack kernel (unchanged layout) ----------------
// whh_pk[tile][ks][lane][j] = W_hh[tile*16 + (lane&15)][ks*32 + (lane>>4)*8 + j]
// wih_pk[tile][ks][lane][j] = W_ih[...same...]
#define N_WHH (128*16*64)
#define N_WIH (128*2*64)
#define N_BIAS 2048
#define N_WFC (512*64)
#define N_PACK (N_WHH + N_WIH + N_BIAS + N_WFC)

__global__ void pack_kernel(const float* __restrict__ W_ih, const float* __restrict__ W_hh,
                            const float* __restrict__ b_ih, const float* __restrict__ b_hh,
                            const float* __restrict__ W_fc,
                            _Float16* __restrict__ whh_pk, _Float16* __restrict__ wih_pk,
                            float* __restrict__ bias, float* __restrict__ wfcT) {
    int tid = blockIdx.x * 256 + threadIdx.x;
    if (tid < N_WHH) {
        int lane = tid & 63, ks = (tid >> 6) & 15, tile = tid >> 10;
        int g = tile * 16 + (lane & 15);
        int k = ks * 32 + (lane >> 4) * 8;
        const float4* src = (const float4*)(W_hh + (size_t)g * HSZ + k);
        float4 v0 = src[0], v1 = src[1];
        f16x8 o;
        o[0] = (_Float16)v0.x; o[1] = (_Float16)v0.y; o[2] = (_Float16)v0.z; o[3] = (_Float16)v0.w;
        o[4] = (_Float16)v1.x; o[5] = (_Float16)v1.y; o[6] = (_Float16)v1.z; o[7] = (_Float16)v1.w;
        *(f16x8*)(whh_pk + (size_t)tid * 8) = o;
        return;
    }
    tid -= N_WHH;
    if (tid < N_WIH) {
        int lane = tid & 63, ks = (tid >> 6) & 1, tile = tid >> 7;
        int g = tile * 16 + (lane & 15);
        int k = ks * 32 + (lane >> 4) * 8;
        const float4* src = (const float4*)(W_ih + (size_t)g * ISZ + k);
        float4 v0 = src[0], v1 = src[1];
        f16x8 o;
        o[0] = (_Float16)v0.x; o[1] = (_Float16)v0.y; o[2] = (_Float16)v0.z; o[3] = (_Float16)v0.w;
        o[4] = (_Float16)v1.x; o[5] = (_Float16)v1.y; o[6] = (_Float16)v1.z; o[7] = (_Float16)v1.w;
        *(f16x8*)(wih_pk + (size_t)tid * 8) = o;
        return;
    }
    tid -= N_WIH;
    if (tid < N_BIAS) { bias[tid] = b_ih[tid] + b_hh[tid]; return; }
    tid -= N_BIAS;
    if (tid < N_WFC) {
        int j = tid >> 6, o = tid & 63;
        wfcT[j * 64 + o] = W_fc[o * HSZ + j];
    }
}

// ---------------- init: zero h(0) + barrier counters (every call) ----------------
__global__ void init_kernel(float* __restrict__ hg0, unsigned* __restrict__ cnt) {
    int tid = blockIdx.x * 256 + threadIdx.x;
    if (tid < 65536) hg0[tid] = 0.f;                      // h_glob buf 0: 256 KB
    if (blockIdx.x == 0 && threadIdx.x < 16) cnt[threadIdx.x * 16] = 0u;
}

// ---------------- math ----------------
__device__ __forceinline__ float sigmoid_f(float x) {
    return __builtin_amdgcn_rcpf(1.f + __expf(-x));
}
__device__ __forceinline__ float tanh_f(float x) {
    return 1.f - 2.f * __builtin_amdgcn_rcpf(1.f + __expf(2.f * x));
}

// agent-scope (device-visible, L2-bypass) 16B h-fragment load as 2x u64
__device__ __forceinline__ f16x8 ld_h8_agent(const _Float16* p) {
    union { unsigned long long u[2]; f16x8 v; } r;
    r.u[0] = __hip_atomic_load((const unsigned long long*)p,
                               __ATOMIC_RELAXED, __HIP_MEMORY_SCOPE_AGENT);
    r.u[1] = __hip_atomic_load((const unsigned long long*)(p + 4),
                               __ATOMIC_RELAXED, __HIP_MEMORY_SCOPE_AGENT);
    return r.v;
}

// ---------------- main kernel: 256 blocks x 256 threads (4 waves) ----------------
// bid = hs*16 + bs; group = fixed bs (16 blocks, all hid slices; bid%8 equal
// across group -> same XCD under round-robin, perf-only assumption).
// wave w: p = w>>1 (hid16 half), ro = w&1 (0: gates i,f / 1: gates g,o).
__global__ void __launch_bounds__(256)
__attribute__((amdgpu_waves_per_eu(1, 1)))
lstm_kernel(const float* __restrict__ x,
            const _Float16* whh_pk, const _Float16* wih_pk,
            const float* __restrict__ bias, const float* __restrict__ wfcT,
            const float* __restrict__ b_fc,
            _Float16* h_glob,                       // [2][256][512] f16
            unsigned* __restrict__ cnt,             // [16] stride-16 u32
            float* __restrict__ out) {
    extern __shared__ char smem[];
    _Float16* whh_lds = (_Float16*)(smem + LDS_WHH);
    _Float16* xb      = (_Float16*)(smem + LDS_XB);    // [2][16*XPITCH]
    float*    pl      = (float*)   (smem + LDS_PL);
    _Float16* hst     = (_Float16*)(smem + LDS_HST);

    const int tid  = threadIdx.x;
    const int lane = tid & 63;
    const int w    = tid >> 6;        // wave 0..3
    const int p    = w >> 1;          // hid16 half 0..1
    const int ro   = w & 1;           // 0: i,f   1: g,o
    const int col  = lane & 15;
    const int kg   = lane >> 4;
    const int bid  = blockIdx.x;
    const int hs   = bid >> 4;        // hid slice 0..15 (32 hids)
    const int bs   = bid & 15;        // batch slice 0..15
    const int brow0 = bs * 16;

    // ---- stage W_hh slice -> LDS, once (8 local tiles x 16 ks) ----
    // local tile L = gb*2 + p  (gb = L>>1, p = L&1); global tile = gb*32 + hs*2 + p
    for (int i = tid; i < 8192; i += 256) {
        const int L = i >> 10, ks = (i >> 6) & 15, ln = i & 63;
        const int tg = (L >> 1) * 32 + hs * 2 + (L & 1);
        *(f16x8*)&whh_lds[(size_t)i * 8] =
            *(const f16x8*)&whh_pk[(((size_t)tg * 16 + ks) * 64 + ln) * 8];
    }

    // ---- W_ih fragments -> regs (2 gates x 2 ks = 16 VGPR) ----
    f16x8 wihv[2][2];
    #pragma unroll
    for (int a = 0; a < 2; ++a) {
        const int tg = (2 * ro + a) * 32 + hs * 2 + p;
        #pragma unroll
        for (int ks = 0; ks < 2; ++ks)
            wihv[a][ks] = *(const f16x8*)&wih_pk[(((size_t)tg * 2 + ks) * 64 + lane) * 8];
    }
    KEEP(wihv[0][0]); KEEP(wihv[0][1]); KEEP(wihv[1][0]); KEEP(wihv[1][1]);

    // bias for this wave's 2 gate tiles (hid = hs*32 + p*16 + col)
    float bia[2];
    #pragma unroll
    for (int a = 0; a < 2; ++a)
        bia[a] = bias[(2 * ro + a) * 512 + hs * 32 + p * 16 + col];

    // x staging: 16 rows x 64 f32, one float4 per thread
    const int xs_row = tid >> 4;
    const int xs_col = (tid & 15) * 4;
    const float* xs_base = x + ((size_t)(brow0 + xs_row) * T_STEPS) * ISZ + xs_col;
    {
        float4 v = *(const float4*)xs_base;
        f16x4 h4 = {(_Float16)v.x, (_Float16)v.y, (_Float16)v.z, (_Float16)v.w};
        *(f16x4*)&xb[xs_row * XPITCH + xs_col] = h4;
    }

    // c state (ro==0 waves): (batch 4*kg+r, hid hs*32 + p*16 + col)
    f32x4 cst = (f32x4){0.f, 0.f, 0.f, 0.f};

    unsigned* mycnt = cnt + bs * 16;

    // per-wave LDS weight base pointers (L0 = gates i/g, L1 = f/o per role)
    const int L0 = (2 * ro) * 2 + p, L1 = (2 * ro + 1) * 2 + p;
    const _Float16* wb0 = whh_lds + ((size_t)L0 * 1024 + lane) * 8;
    const _Float16* wb1 = whh_lds + ((size_t)L1 * 1024 + lane) * 8;

    __syncthreads();   // weight staging + xb[0] visible

    for (int t = 0; t < T_STEPS; ++t) {
        const int cur = t & 1, nxt = cur ^ 1;
        const _Float16* xbc = xb + cur * (16 * XPITCH);
        _Float16*       xbn = xb + nxt * (16 * XPITCH);

        // x(t+1) prefetch
        float4 xv;
        const bool havex = (t + 1) < T_STEPS;
        if (havex) xv = *(const float4*)(xs_base + (size_t)(t + 1) * ISZ);

        // ---- h(t) fragments via agent loads (all 16 ks issued up front) ----
        const _Float16* hrow = h_glob + ((size_t)cur * BATCH + brow0 + col) * HSZ;
        f16x8 ah[16];
        #pragma unroll
        for (int ks = 0; ks < 16; ++ks)
            ah[ks] = ld_h8_agent(hrow + ks * 32 + kg * 8);

        f16x8 ax0 = *(const f16x8*)&xbc[col * XPITCH + kg * 8];
        f16x8 ax1 = *(const f16x8*)&xbc[col * XPITCH + 32 + kg * 8];

        // ---- 36 MFMA: bias in C-init; x part; then 16 hh ks from LDS ----
        f32x4 acc[2];
        acc[0] = (f32x4){bia[0], bia[0], bia[0], bia[0]};
        acc[1] = (f32x4){bia[1], bia[1], bia[1], bia[1]};
        acc[0] = __builtin_amdgcn_mfma_f32_16x16x32_f16(ax0, wihv[0][0], acc[0], 0, 0, 0);
        acc[0] = __builtin_amdgcn_mfma_f32_16x16x32_f16(ax1, wihv[0][1], acc[0], 0, 0, 0);
        acc[1] = __builtin_amdgcn_mfma_f32_16x16x32_f16(ax0, wihv[1][0], acc[1], 0, 0, 0);
        acc[1] = __builtin_amdgcn_mfma_f32_16x16x32_f16(ax1, wihv[1][1], acc[1], 0, 0, 0);
        #pragma unroll
        for (int ks = 0; ks < 16; ++ks) {
            f16x8 w0 = *(const f16x8*)(wb0 + (size_t)ks * 512);
            f16x8 w1 = *(const f16x8*)(wb1 + (size_t)ks * 512);
            acc[0] = __builtin_amdgcn_mfma_f32_16x16x32_f16(ah[ks], w0, acc[0], 0, 0, 0);
            acc[1] = __builtin_amdgcn_mfma_f32_16x16x32_f16(ah[ks], w1, acc[1], 0, 0, 0);
        }

        // ---- g,o tiles -> LDS partials ----
        if (ro == 1) {
            #pragma unroll
            for (int a = 0; a < 2; ++a)
                *(f32x4*)&pl[((p * 2 + a) * 16 + col) * PLP + kg * 4] = acc[a];
        }
        __syncthreads();   // S1: partials visible; xb[cur] reads done

        if (havex) {
            f16x4 h4 = {(_Float16)xv.x, (_Float16)xv.y, (_Float16)xv.z, (_Float16)xv.w};
            *(f16x4*)&xbn[xs_row * XPITCH + xs_col] = h4;
        }

        // ---- ro==0 waves: cell update (i,f in-reg; g,o from LDS) ----
        if (ro == 0) {
            f32x4 gv4 = *(const f32x4*)&pl[((p * 2 + 0) * 16 + col) * PLP + kg * 4];
            f32x4 ov4 = *(const f32x4*)&pl[((p * 2 + 1) * 16 + col) * PLP + kg * 4];
            #pragma unroll
            for (int r = 0; r < 4; ++r) {
                float iv = sigmoid_f(acc[0][r]);
                float fv = sigmoid_f(acc[1][r]);
                float gv = tanh_f   (gv4[r]);
                float ov = sigmoid_f(ov4[r]);
                float c  = fv * cst[r] + iv * gv;
                cst[r] = c;
                float hv = ov * tanh_f(c);
                hst[(4 * kg + r) * 32 + p * 16 + col] = (_Float16)hv;
            }
        }
        __syncthreads();   // S2: hst complete

        // ---- cooperative coalesced agent store: 256 threads x one u32 ----
        {
            const int b   = tid >> 4;       // batch row 0..15
            const int c16 = tid & 15;       // u32 column 0..15 (32 f16)
            unsigned v = *(const unsigned*)&hst[b * 32 + c16 * 2];
            unsigned* dst = (unsigned*)(h_glob + ((size_t)nxt * BATCH + brow0 + b) * HSZ + hs * 32) + c16;
            __hip_atomic_store(dst, v, __ATOMIC_RELAXED, __HIP_MEMORY_SCOPE_AGENT);
        }
        __syncthreads();   // S3: implicit vmcnt(0) drains agent stores (release)

        // ---- group barrier: 16 arrivals, no fences ----
        if (tid == 0) {
            atomicAdd(mycnt, 1u);           // device-scope, relaxed
            const unsigned target = 16u * (unsigned)(t + 1);
            int it = 0;
            while (__hip_atomic_load(mycnt, __ATOMIC_RELAXED, __HIP_MEMORY_SCOPE_AGENT) < target) {
                __builtin_amdgcn_s_sleep(1);
                if (++it > 20000) break;    // safety bail (bug -> wrong, not hung)
            }
        }
        __syncthreads();   // S4: block released
    }

    // ---- FC epilogue on hs==0 blocks; final h is in buffer 0 (T even) ----
    if (hs == 0) {
        #pragma unroll
        for (int rr = 0; rr < 4; ++rr) {
            const int m = w * 4 + rr;
            const _Float16* hr = h_glob + (size_t)(brow0 + m) * HSZ;
            float acco = b_fc[lane];
            for (int j8 = 0; j8 < HSZ / 8; ++j8) {
                f16x8 hv8 = ld_h8_agent(hr + j8 * 8);
                #pragma unroll
                for (int j = 0; j < 8; ++j) {
                    float hv = fmaxf((float)hv8[j], 0.f);
                    acco = fmaf(hv, wfcT[(j8 * 8 + j) * 64 + lane], acco);
                }
            }
            out[(size_t)(brow0 + m) * OSZ + lane] = acco;
        }
    }
}

// ---------------- launch ----------------
extern "C" void kernel_launch(void* const* d_in, const int* in_sizes, int n_in,
                              void* d_out, int out_size, void* d_ws, size_t ws_size,
                              hipStream_t stream) {
    (void)in_sizes; (void)n_in; (void)out_size; (void)ws_size;
    const float* x    = (const float*)d_in[0];
    const float* W_ih = (const float*)d_in[1];
    const float* W_hh = (const float*)d_in[2];
    const float* b_ih = (const float*)d_in[3];
    const float* b_hh = (const float*)d_in[4];
    const float* W_fc = (const float*)d_in[5];
    const float* b_fc = (const float*)d_in[6];
    float* out = (float*)d_out;

    char* wsb = (char*)d_ws;
    _Float16* whh_pk = (_Float16*)(wsb + OFF_WHH);
    _Float16* wih_pk = (_Float16*)(wsb + OFF_WIH);
    float*    bias   = (float*)   (wsb + OFF_BIAS);
    float*    wfcT   = (float*)   (wsb + OFF_WFCT);
    _Float16* h_glob = (_Float16*)(wsb + OFF_H);
    unsigned* cnt    = (unsigned*)(wsb + OFF_CNT);

    // raise dynamic-LDS cap (host-side, idempotent, not stream-captured)
    hipFuncSetAttribute(reinterpret_cast<const void*>(lstm_kernel),
                        hipFuncAttributeMaxDynamicSharedMemorySize, LDS_TOTAL);

    hipLaunchKernelGGL(pack_kernel, dim3((N_PACK + 255) / 256), dim3(256), 0, stream,
                       W_ih, W_hh, b_ih, b_hh, W_fc, whh_pk, wih_pk, bias, wfcT);
    hipLaunchKernelGGL(init_kernel, dim3(256), dim3(256), 0, stream,
                       (float*)(wsb + OFF_H), cnt);
    hipLaunchKernelGGL(lstm_kernel, dim3(256), dim3(256), LDS_TOTAL, stream,
                       x, whh_pk, wih_pk, bias, wfcT, b_fc, h_glob, cnt, out);
}

// Round 11
// 1776.163 us; speedup vs baseline: 9.9901x; 1.5946x over previous
//
#include <hip/hip_runtime.h>
#include <hip/hip_bf16.h>

// LSTM (B=256, T=512, I=64, H=512, O=64) on MI355X — round 11.
// r10 post-mortem: LDS-resident weights NEUTRAL (2.85->2.83ms) -> weight path
// was already hidden; step time is the h-exchange/sync chain through L3.
// THIS ROUND (3 fixes, r10 skeleton + proven sync reasoning kept):
//  1. h-load dedup: block stages h(t) 16KB -> LDS hbuf once (coop agent
//     loads), waves ds_read_b128 fragments. L3 reads 16MB -> 4MB/step.
//  2. flags replace counter: writer stores flg[bs*16+hs]=t+1 (no RMW
//     serialization); wave0 polls 16 flags w/ one coalesced load + __all.
//  3. hot spin (no sleep first 64 iters).
// Barriers/step: S5(hbuf) S1(partials) S2(hst) S3(store drain) S4(release).

#define T_STEPS 512
#define ISZ 64
#define HSZ 512
#define BATCH 256
#define OSZ 64
#define XPITCH 72    // f16 pitch for x staging
#define PLP 20       // dword pitch for g/o partial tile
#define HBP 520      // f16 pitch for hbuf rows (1040B -> 4-bank row shift)

typedef _Float16 f16x8 __attribute__((ext_vector_type(8)));
typedef _Float16 f16x4 __attribute__((ext_vector_type(4)));
typedef float f32x4 __attribute__((ext_vector_type(4)));

#define KEEP(v) asm volatile("" : "+v"(v))

// ---------------- workspace layout ----------------
#define OFF_WHH  0u          // 2 MB   fp16 packed W_hh fragments
#define OFF_WIH  2097152u    // 256 KB fp16 packed W_ih fragments
#define OFF_BIAS 2359296u    // 8 KB   f32 b_ih+b_hh
#define OFF_WFCT 2367488u    // 128 KB f32 W_fc transposed
#define OFF_H    2498560u    // 512 KB f16 h_glob[2][256][512]
#define OFF_FLG  3022848u    // 1 KB   u32 flg[16 groups][16 blocks]

// ---------------- dynamic-LDS partition ----------------
#define LDS_WHH   0u         // 131072 B : 8 tiles x 16 ks x 64 lanes x 16 B
#define LDS_XB    131072u    //   4608 B : 2 x 16 x 72 f16
#define LDS_PL    135680u    //   5120 B : g/o partials, 4 tiles x 16 x 20 dw
#define LDS_HST   140800u    //   1024 B : 16 x 32 f16 h staging
#define LDS_HBUF  141824u    //  16640 B : 16 x 520 f16 h(t) tile
#define LDS_TOTAL 158464u

// ---------------- pack kernel (unchanged layout) ----------------
// whh_pk[tile][ks][lane][j] = W_hh[tile*16 + (lane&15)][ks*32 + (lane>>4)*8 + j]
// wih_pk[tile][ks][lane][j] = W_ih[...same...]
#define N_WHH (128*16*64)
#define N_WIH (128*2*64)
#define N_BIAS 2048
#define N_WFC (512*64)
#define N_PACK (N_WHH + N_WIH + N_BIAS + N_WFC)

__global__ void pack_kernel(const float* __restrict__ W_ih, const float* __restrict__ W_hh,
                            const float* __restrict__ b_ih, const float* __restrict__ b_hh,
                            const float* __restrict__ W_fc,
                            _Float16* __restrict__ whh_pk, _Float16* __restrict__ wih_pk,
                            float* __restrict__ bias, float* __restrict__ wfcT) {
    int tid = blockIdx.x * 256 + threadIdx.x;
    if (tid < N_WHH) {
        int lane = tid & 63, ks = (tid >> 6) & 15, tile = tid >> 10;
        int g = tile * 16 + (lane & 15);
        int k = ks * 32 + (lane >> 4) * 8;
        const float4* src = (const float4*)(W_hh + (size_t)g * HSZ + k);
        float4 v0 = src[0], v1 = src[1];
        f16x8 o;
        o[0] = (_Float16)v0.x; o[1] = (_Float16)v0.y; o[2] = (_Float16)v0.z; o[3] = (_Float16)v0.w;
        o[4] = (_Float16)v1.x; o[5] = (_Float16)v1.y; o[6] = (_Float16)v1.z; o[7] = (_Float16)v1.w;
        *(f16x8*)(whh_pk + (size_t)tid * 8) = o;
        return;
    }
    tid -= N_WHH;
    if (tid < N_WIH) {
        int lane = tid & 63, ks = (tid >> 6) & 1, tile = tid >> 7;
        int g = tile * 16 + (lane & 15);
        int k = ks * 32 + (lane >> 4) * 8;
        const float4* src = (const float4*)(W_ih + (size_t)g * ISZ + k);
        float4 v0 = src[0], v1 = src[1];
        f16x8 o;
        o[0] = (_Float16)v0.x; o[1] = (_Float16)v0.y; o[2] = (_Float16)v0.z; o[3] = (_Float16)v0.w;
        o[4] = (_Float16)v1.x; o[5] = (_Float16)v1.y; o[6] = (_Float16)v1.z; o[7] = (_Float16)v1.w;
        *(f16x8*)(wih_pk + (size_t)tid * 8) = o;
        return;
    }
    tid -= N_WIH;
    if (tid < N_BIAS) { bias[tid] = b_ih[tid] + b_hh[tid]; return; }
    tid -= N_BIAS;
    if (tid < N_WFC) {
        int j = tid >> 6, o = tid & 63;
        wfcT[j * 64 + o] = W_fc[o * HSZ + j];
    }
}

// ---------------- init: zero h(0) + flags (every call; graph-replay safe) ----------------
__global__ void init_kernel(float* __restrict__ hg0, unsigned* __restrict__ flg) {
    int tid = blockIdx.x * 256 + threadIdx.x;
    if (tid < 65536) hg0[tid] = 0.f;                      // h_glob buf 0: 256 KB
    if (blockIdx.x == 0 && threadIdx.x < 256) flg[threadIdx.x] = 0u;
}

// ---------------- math ----------------
__device__ __forceinline__ float sigmoid_f(float x) {
    return __builtin_amdgcn_rcpf(1.f + __expf(-x));
}
__device__ __forceinline__ float tanh_f(float x) {
    return 1.f - 2.f * __builtin_amdgcn_rcpf(1.f + __expf(2.f * x));
}

// agent-scope (device-visible, L2-bypass) u64 load
__device__ __forceinline__ unsigned long long ld_u64_agent(const void* p) {
    return __hip_atomic_load((const unsigned long long*)p,
                             __ATOMIC_RELAXED, __HIP_MEMORY_SCOPE_AGENT);
}
__device__ __forceinline__ f16x8 ld_h8_agent(const _Float16* p) {
    union { unsigned long long u[2]; f16x8 v; } r;
    r.u[0] = ld_u64_agent(p);
    r.u[1] = ld_u64_agent(p + 4);
    return r.v;
}

// ---------------- main kernel: 256 blocks x 256 threads (4 waves) ----------------
// bid = hs*16 + bs; group = fixed bs (16 blocks, all hid slices).
// wave w: p = w>>1 (hid16 half), ro = w&1 (0: gates i,f / 1: gates g,o).
__global__ void __launch_bounds__(256)
__attribute__((amdgpu_waves_per_eu(1, 1)))
lstm_kernel(const float* __restrict__ x,
            const _Float16* whh_pk, const _Float16* wih_pk,
            const float* __restrict__ bias, const float* __restrict__ wfcT,
            const float* __restrict__ b_fc,
            _Float16* h_glob,                       // [2][256][512] f16
            unsigned* __restrict__ flg,             // [16][16] u32
            float* __restrict__ out) {
    extern __shared__ char smem[];
    _Float16* whh_lds = (_Float16*)(smem + LDS_WHH);
    _Float16* xb      = (_Float16*)(smem + LDS_XB);    // [2][16*XPITCH]
    float*    pl      = (float*)   (smem + LDS_PL);
    _Float16* hst     = (_Float16*)(smem + LDS_HST);
    _Float16* hbuf    = (_Float16*)(smem + LDS_HBUF);  // [16][HBP]

    const int tid  = threadIdx.x;
    const int lane = tid & 63;
    const int w    = tid >> 6;        // wave 0..3
    const int p    = w >> 1;          // hid16 half 0..1
    const int ro   = w & 1;           // 0: i,f   1: g,o
    const int col  = lane & 15;
    const int kg   = lane >> 4;
    const int bid  = blockIdx.x;
    const int hs   = bid >> 4;        // hid slice 0..15 (32 hids)
    const int bs   = bid & 15;        // batch slice 0..15
    const int brow0 = bs * 16;

    // ---- stage W_hh slice -> LDS, once ----
    for (int i = tid; i < 8192; i += 256) {
        const int L = i >> 10, ks = (i >> 6) & 15, ln = i & 63;
        const int tg = (L >> 1) * 32 + hs * 2 + (L & 1);
        *(f16x8*)&whh_lds[(size_t)i * 8] =
            *(const f16x8*)&whh_pk[(((size_t)tg * 16 + ks) * 64 + ln) * 8];
    }

    // ---- W_ih fragments -> regs ----
    f16x8 wihv[2][2];
    #pragma unroll
    for (int a = 0; a < 2; ++a) {
        const int tg = (2 * ro + a) * 32 + hs * 2 + p;
        #pragma unroll
        for (int ks = 0; ks < 2; ++ks)
            wihv[a][ks] = *(const f16x8*)&wih_pk[(((size_t)tg * 2 + ks) * 64 + lane) * 8];
    }
    KEEP(wihv[0][0]); KEEP(wihv[0][1]); KEEP(wihv[1][0]); KEEP(wihv[1][1]);

    float bia[2];
    #pragma unroll
    for (int a = 0; a < 2; ++a)
        bia[a] = bias[(2 * ro + a) * 512 + hs * 32 + p * 16 + col];

    // x staging: 16 rows x 64 f32, one float4 per thread
    const int xs_row = tid >> 4;
    const int xs_col = (tid & 15) * 4;
    const float* xs_base = x + ((size_t)(brow0 + xs_row) * T_STEPS) * ISZ + xs_col;
    {
        float4 v = *(const float4*)xs_base;
        f16x4 h4 = {(_Float16)v.x, (_Float16)v.y, (_Float16)v.z, (_Float16)v.w};
        *(f16x4*)&xb[xs_row * XPITCH + xs_col] = h4;
    }

    // c state (ro==0 waves)
    f32x4 cst = (f32x4){0.f, 0.f, 0.f, 0.f};

    // per-wave LDS weight base pointers
    const int L0 = (2 * ro) * 2 + p, L1 = (2 * ro + 1) * 2 + p;
    const _Float16* wb0 = whh_lds + ((size_t)L0 * 1024 + lane) * 8;
    const _Float16* wb1 = whh_lds + ((size_t)L1 * 1024 + lane) * 8;

    // hbuf stage mapping: row = tid>>4, 64B segment = tid&15
    const int hb_row = tid >> 4;
    const int hb_seg = tid & 15;
    const _Float16* hg0 = h_glob + ((size_t)0 * BATCH + brow0 + hb_row) * HSZ + hb_seg * 32;
    const _Float16* hg1 = h_glob + ((size_t)1 * BATCH + brow0 + hb_row) * HSZ + hb_seg * 32;
    _Float16* hbw = hbuf + hb_row * HBP + hb_seg * 32;

    unsigned* myflg = flg + bs * 16;

    __syncthreads();   // weights + xb[0] visible

    for (int t = 0; t < T_STEPS; ++t) {
        const int cur = t & 1, nxt = cur ^ 1;
        const _Float16* xbc = xb + cur * (16 * XPITCH);
        _Float16*       xbn = xb + nxt * (16 * XPITCH);

        // ---- stage h(t) -> hbuf: 256 threads x 64B agent loads (dedup) ----
        {
            const _Float16* src = cur ? hg1 : hg0;
            unsigned long long u0 = ld_u64_agent(src);
            unsigned long long u1 = ld_u64_agent(src + 4);
            unsigned long long u2 = ld_u64_agent(src + 8);
            unsigned long long u3 = ld_u64_agent(src + 12);
            unsigned long long u4 = ld_u64_agent(src + 16);
            unsigned long long u5 = ld_u64_agent(src + 20);
            unsigned long long u6 = ld_u64_agent(src + 24);
            unsigned long long u7 = ld_u64_agent(src + 28);
            ((unsigned long long*)hbw)[0] = u0; ((unsigned long long*)hbw)[1] = u1;
            ((unsigned long long*)hbw)[2] = u2; ((unsigned long long*)hbw)[3] = u3;
            ((unsigned long long*)hbw)[4] = u4; ((unsigned long long*)hbw)[5] = u5;
            ((unsigned long long*)hbw)[6] = u6; ((unsigned long long*)hbw)[7] = u7;
        }

        // x(t+1) prefetch
        float4 xv;
        const bool havex = (t + 1) < T_STEPS;
        if (havex) xv = *(const float4*)(xs_base + (size_t)(t + 1) * ISZ);

        __syncthreads();   // S5: hbuf ready

        f16x8 ax0 = *(const f16x8*)&xbc[col * XPITCH + kg * 8];
        f16x8 ax1 = *(const f16x8*)&xbc[col * XPITCH + 32 + kg * 8];

        // ---- 36 MFMA: bias C-init, x part, 16 hh ks (A from hbuf, B from LDS) ----
        f32x4 acc[2];
        acc[0] = (f32x4){bia[0], bia[0], bia[0], bia[0]};
        acc[1] = (f32x4){bia[1], bia[1], bia[1], bia[1]};
        acc[0] = __builtin_amdgcn_mfma_f32_16x16x32_f16(ax0, wihv[0][0], acc[0], 0, 0, 0);
        acc[0] = __builtin_amdgcn_mfma_f32_16x16x32_f16(ax1, wihv[0][1], acc[0], 0, 0, 0);
        acc[1] = __builtin_amdgcn_mfma_f32_16x16x32_f16(ax0, wihv[1][0], acc[1], 0, 0, 0);
        acc[1] = __builtin_amdgcn_mfma_f32_16x16x32_f16(ax1, wihv[1][1], acc[1], 0, 0, 0);
        const _Float16* hrow = hbuf + col * HBP + kg * 8;
        #pragma unroll
        for (int ks = 0; ks < 16; ++ks) {
            f16x8 ah = *(const f16x8*)(hrow + ks * 32);
            f16x8 w0 = *(const f16x8*)(wb0 + (size_t)ks * 512);
            f16x8 w1 = *(const f16x8*)(wb1 + (size_t)ks * 512);
            acc[0] = __builtin_amdgcn_mfma_f32_16x16x32_f16(ah, w0, acc[0], 0, 0, 0);
            acc[1] = __builtin_amdgcn_mfma_f32_16x16x32_f16(ah, w1, acc[1], 0, 0, 0);
        }

        // ---- g,o tiles -> LDS partials ----
        if (ro == 1) {
            #pragma unroll
            for (int a = 0; a < 2; ++a)
                *(f32x4*)&pl[((p * 2 + a) * 16 + col) * PLP + kg * 4] = acc[a];
        }
        __syncthreads();   // S1: partials visible; hbuf/xb[cur] reads done

        if (havex) {
            f16x4 h4 = {(_Float16)xv.x, (_Float16)xv.y, (_Float16)xv.z, (_Float16)xv.w};
            *(f16x4*)&xbn[xs_row * XPITCH + xs_col] = h4;
        }

        // ---- ro==0 waves: cell update (i,f in-reg; g,o from LDS) ----
        if (ro == 0) {
            f32x4 gv4 = *(const f32x4*)&pl[((p * 2 + 0) * 16 + col) * PLP + kg * 4];
            f32x4 ov4 = *(const f32x4*)&pl[((p * 2 + 1) * 16 + col) * PLP + kg * 4];
            #pragma unroll
            for (int r = 0; r < 4; ++r) {
                float iv = sigmoid_f(acc[0][r]);
                float fv = sigmoid_f(acc[1][r]);
                float gv = tanh_f   (gv4[r]);
                float ov = sigmoid_f(ov4[r]);
                float c  = fv * cst[r] + iv * gv;
                cst[r] = c;
                float hv = ov * tanh_f(c);
                hst[(4 * kg + r) * 32 + p * 16 + col] = (_Float16)hv;
            }
        }
        __syncthreads();   // S2: hst complete

        // ---- cooperative coalesced agent store: 256 threads x one u32 ----
        {
            const int b   = tid >> 4;
            const int c16 = tid & 15;
            unsigned v = *(const unsigned*)&hst[b * 32 + c16 * 2];
            unsigned* dst = (unsigned*)(h_glob + ((size_t)nxt * BATCH + brow0 + b) * HSZ + hs * 32) + c16;
            __hip_atomic_store(dst, v, __ATOMIC_RELAXED, __HIP_MEMORY_SCOPE_AGENT);
        }
        __syncthreads();   // S3: vmcnt(0) drain of all waves' h stores (release)

        // ---- arrive: one flag store (no RMW); wave0 polls 16 flags ----
        if (tid == 0)
            __hip_atomic_store(&myflg[hs], (unsigned)(t + 1),
                               __ATOMIC_RELAXED, __HIP_MEMORY_SCOPE_AGENT);
        if (w == 0) {
            const unsigned tgt = (unsigned)(t + 1);
            int it = 0;
            for (;;) {
                unsigned f = (lane < 16)
                    ? __hip_atomic_load(&myflg[lane], __ATOMIC_RELAXED, __HIP_MEMORY_SCOPE_AGENT)
                    : tgt;
                if (__all(f >= tgt)) break;
                if (++it > 50000) break;            // safety bail
                if (it > 64) __builtin_amdgcn_s_sleep(1);
            }
        }
        __syncthreads();   // S4: block released; h(t+1) visible at L3
    }

    // ---- FC epilogue on hs==0 blocks; final h is in buffer 0 (T even) ----
    if (hs == 0) {
        #pragma unroll
        for (int rr = 0; rr < 4; ++rr) {
            const int m = w * 4 + rr;
            const _Float16* hr = h_glob + (size_t)(brow0 + m) * HSZ;
            float acco = b_fc[lane];
            for (int j8 = 0; j8 < HSZ / 8; ++j8) {
                f16x8 hv8 = ld_h8_agent(hr + j8 * 8);
                #pragma unroll
                for (int j = 0; j < 8; ++j) {
                    float hv = fmaxf((float)hv8[j], 0.f);
                    acco = fmaf(hv, wfcT[(j8 * 8 + j) * 64 + lane], acco);
                }
            }
            out[(size_t)(brow0 + m) * OSZ + lane] = acco;
        }
    }
}

// ---------------- launch ----------------
extern "C" void kernel_launch(void* const* d_in, const int* in_sizes, int n_in,
                              void* d_out, int out_size, void* d_ws, size_t ws_size,
                              hipStream_t stream) {
    (void)in_sizes; (void)n_in; (void)out_size; (void)ws_size;
    const float* x    = (const float*)d_in[0];
    const float* W_ih = (const float*)d_in[1];
    const float* W_hh = (const float*)d_in[2];
    const float* b_ih = (const float*)d_in[3];
    const float* b_hh = (const float*)d_in[4];
    const float* W_fc = (const float*)d_in[5];
    const float* b_fc = (const float*)d_in[6];
    float* out = (float*)d_out;

    char* wsb = (char*)d_ws;
    _Float16* whh_pk = (_Float16*)(wsb + OFF_WHH);
    _Float16* wih_pk = (_Float16*)(wsb + OFF_WIH);
    float*    bias   = (float*)   (wsb + OFF_BIAS);
    float*    wfcT   = (float*)   (wsb + OFF_WFCT);
    _Float16* h_glob = (_Float16*)(wsb + OFF_H);
    unsigned* flg    = (unsigned*)(wsb + OFF_FLG);

    // raise dynamic-LDS cap (host-side, idempotent, not stream-captured)
    hipFuncSetAttribute(reinterpret_cast<const void*>(lstm_kernel),
                        hipFuncAttributeMaxDynamicSharedMemorySize, LDS_TOTAL);

    hipLaunchKernelGGL(pack_kernel, dim3((N_PACK + 255) / 256), dim3(256), 0, stream,
                       W_ih, W_hh, b_ih, b_hh, W_fc, whh_pk, wih_pk, bias, wfcT);
    hipLaunchKernelGGL(init_kernel, dim3(256), dim3(256), 0, stream,
                       (float*)(wsb + OFF_H), flg);
    hipLaunchKernelGGL(lstm_kernel, dim3(256), dim3(256), LDS_TOTAL, stream,
                       x, whh_pk, wih_pk, bias, wfcT, b_fc, h_glob, flg, out);
}